// Round 3
// baseline (875.457 us; speedup 1.0000x reference)
//
#include <hip/hip_runtime.h>
#include <hip/hip_bf16.h>

#define NB 1024
#define SS 256
#define LL 256
#define HH 128
#define KMAX 16
#define KE 8
#define LOWPAD 132   // fp32 row stride: 132*4=528B (16B-aligned, not 512B-periodic)

__global__ __launch_bounds__(512) void capsule_fused(
    const float* __restrict__ inputs,      // [B][S][L]
    const int*   __restrict__ seq_len,     // [B]
    const float* __restrict__ Wm,          // [L][H]
    const float* __restrict__ r_init,      // [B][S][KMAX]
    float* __restrict__ out)               // fp32: [B*KMAX*H] ++ [B*KMAX]
{
  __shared__ __align__(16) float s_low[SS][LOWPAD];   // 135168 B
  __shared__ __align__(16) float s_p[SS][KE];         //   8192 B
  __shared__ __align__(16) float s_part[2][KE][HH];   //   8192 B
  __shared__ __align__(16) float s_high[KE][HH];      //   4096 B
  __shared__ __align__(16) float s_inv[SS];           //   1024 B
  __shared__ __align__(16) float s_scale[KE];         //     32 B

  const int b = blockIdx.x;
  const int t = threadIdx.x;
  const int sl = seq_len[b];

  // n_high = clamp(log2(sl), 1, 16); active capsules k < n_high (<= 8 for sl <= 256)
  const int ilog = 31 - __clz(sl);
  float nh = ((sl & (sl - 1)) == 0) ? (float)ilog : log2f((float)sl);
  nh = fmaxf(1.0f, fminf(16.0f, nh));
  const int ka = (int)ceilf(nh);

  // ---------------- Phase 1: low = inputs[b] @ W -----------------------------
  {
    const int hg = t & 15;                 // 16 h-groups of 8
    const int h0 = hg * 8;
    const int rg = t >> 4;                 // 32 rows per sweep
    const float* inb = inputs + (size_t)b * SS * LL;
    for (int sweep = 0; sweep < 8; ++sweep) {
      const int s = sweep * 32 + rg;
      float acc0 = 0.f, acc1 = 0.f, acc2 = 0.f, acc3 = 0.f;
      float acc4 = 0.f, acc5 = 0.f, acc6 = 0.f, acc7 = 0.f;
      if (s < sl) {                        // masked rows stay exactly 0
        const float* inp = inb + (size_t)s * LL;
        for (int l = 0; l < LL; l += 4) {
          const float4 iv = *(const float4*)(inp + l);
          #pragma unroll
          for (int d = 0; d < 4; ++d) {
            const float f = (d == 0) ? iv.x : (d == 1) ? iv.y : (d == 2) ? iv.z : iv.w;
            const float* wp = Wm + (size_t)(l + d) * HH + h0;
            const float4 wa = *(const float4*)(wp);
            const float4 wb = *(const float4*)(wp + 4);
            acc0 = fmaf(f, wa.x, acc0);
            acc1 = fmaf(f, wa.y, acc1);
            acc2 = fmaf(f, wa.z, acc2);
            acc3 = fmaf(f, wa.w, acc3);
            acc4 = fmaf(f, wb.x, acc4);
            acc5 = fmaf(f, wb.y, acc5);
            acc6 = fmaf(f, wb.z, acc6);
            acc7 = fmaf(f, wb.w, acc7);
          }
        }
      }
      s_low[s][h0 + 0] = acc0;  s_low[s][h0 + 1] = acc1;
      s_low[s][h0 + 2] = acc2;  s_low[s][h0 + 3] = acc3;
      s_low[s][h0 + 4] = acc4;  s_low[s][h0 + 5] = acc5;
      s_low[s][h0 + 6] = acc6;  s_low[s][h0 + 7] = acc7;
    }
  }

  // routing logits init (only k<8 ever active)
  for (int idx = t; idx < SS * KE; idx += 512) {
    const int s = idx >> 3, k = idx & 7;
    s_p[s][k] = r_init[((size_t)b * SS + s) * KMAX + k];
  }
  __syncthreads();

  // row inverse norms (serial per row: simple and race-free)
  if (t < SS) {
    float n2 = 0.f;
    for (int h = 0; h < HH; ++h) {
      const float v = s_low[t][h];
      n2 = fmaf(v, v, n2);
    }
    s_inv[t] = 1.0f / fmaxf(sqrtf(n2), 1e-12f);
  }
  __syncthreads();

  // ---------------- Phase 2: 3 routing iterations ---------------------------
  for (int it = 0; it < 3; ++it) {
    // (a) softmax over active k, zeroed for masked rows
    if (t < SS) {
      const int s = t;
      float rk0 = s_p[s][0], rk1 = s_p[s][1], rk2 = s_p[s][2], rk3 = s_p[s][3];
      float rk4 = s_p[s][4], rk5 = s_p[s][5], rk6 = s_p[s][6], rk7 = s_p[s][7];
      float m = rk0;                        // ka >= 1 always
      if (1 < ka) m = fmaxf(m, rk1);
      if (2 < ka) m = fmaxf(m, rk2);
      if (3 < ka) m = fmaxf(m, rk3);
      if (4 < ka) m = fmaxf(m, rk4);
      if (5 < ka) m = fmaxf(m, rk5);
      if (6 < ka) m = fmaxf(m, rk6);
      if (7 < ka) m = fmaxf(m, rk7);
      float e0 = expf(rk0 - m);
      float e1 = (1 < ka) ? expf(rk1 - m) : 0.f;
      float e2 = (2 < ka) ? expf(rk2 - m) : 0.f;
      float e3 = (3 < ka) ? expf(rk3 - m) : 0.f;
      float e4 = (4 < ka) ? expf(rk4 - m) : 0.f;
      float e5 = (5 < ka) ? expf(rk5 - m) : 0.f;
      float e6 = (6 < ka) ? expf(rk6 - m) : 0.f;
      float e7 = (7 < ka) ? expf(rk7 - m) : 0.f;
      const float sum = ((e0 + e1) + (e2 + e3)) + ((e4 + e5) + (e6 + e7));
      const float rs = (s < sl) ? (1.0f / sum) : 0.f;
      s_p[s][0] = e0 * rs;  s_p[s][1] = e1 * rs;
      s_p[s][2] = e2 * rs;  s_p[s][3] = e3 * rs;
      s_p[s][4] = e4 * rs;  s_p[s][5] = e5 * rs;
      s_p[s][6] = e6 * rs;  s_p[s][7] = e7 * rs;
    }
    __syncthreads();

    // (b) high[k][h] = sum_s low[s][h] * p[s][k]  (2 s-groups of 128)
    {
      const int g  = t >> 8;               // 0..1
      const int w4 = (t >> 6) & 3;         // 0..3
      const int k  = (t & 63) >> 3;        // 0..7
      const int hg = t & 7;                // 0..7
      const int h0 = w4 * 32 + hg * 4;
      float a0 = 0.f, a1 = 0.f, a2 = 0.f, a3 = 0.f;
      const int sbase = g * 128;
      for (int i = 0; i < 128; ++i) {
        const int s = sbase + i;
        const float4 v = *(const float4*)&s_low[s][h0];
        const float p = s_p[s][k];
        a0 = fmaf(v.x, p, a0);
        a1 = fmaf(v.y, p, a1);
        a2 = fmaf(v.z, p, a2);
        a3 = fmaf(v.w, p, a3);
      }
      s_part[g][k][h0 + 0] = a0;
      s_part[g][k][h0 + 1] = a1;
      s_part[g][k][h0 + 2] = a2;
      s_part[g][k][h0 + 3] = a3;
    }
    __syncthreads();
    for (int idx = t; idx < KE * HH; idx += 512) {
      const int k = idx >> 7, h = idx & 127;
      s_high[k][h] = s_part[0][k][h] + s_part[1][k][h];
    }
    __syncthreads();

    // (c) r[s][k] = p[s][k] + inv_norm[s] * dot(high[k], low[s])
    if (it < 2) {
      const int s  = t & 255;
      const int k0 = (t >> 8) << 2;        // 0 or 4
      float d0 = 0.f, d1 = 0.f, d2 = 0.f, d3 = 0.f;
      for (int h = 0; h < HH; h += 4) {
        const float4 v  = *(const float4*)&s_low[s][h];
        const float4 q0 = *(const float4*)&s_high[k0 + 0][h];
        const float4 q1 = *(const float4*)&s_high[k0 + 1][h];
        const float4 q2 = *(const float4*)&s_high[k0 + 2][h];
        const float4 q3 = *(const float4*)&s_high[k0 + 3][h];
        d0 = fmaf(v.x, q0.x, fmaf(v.y, q0.y, fmaf(v.z, q0.z, fmaf(v.w, q0.w, d0))));
        d1 = fmaf(v.x, q1.x, fmaf(v.y, q1.y, fmaf(v.z, q1.z, fmaf(v.w, q1.w, d1))));
        d2 = fmaf(v.x, q2.x, fmaf(v.y, q2.y, fmaf(v.z, q2.z, fmaf(v.w, q2.w, d2))));
        d3 = fmaf(v.x, q3.x, fmaf(v.y, q3.y, fmaf(v.w, q3.w, fmaf(v.z, q3.z, d3))));
      }
      // note: order of the last fmaf chain for d3 is immaterial (fp32 assoc differences ~1ulp)
      const float inv = s_inv[s];
      s_p[s][k0 + 0] = fmaf(d0, inv, s_p[s][k0 + 0]);
      s_p[s][k0 + 1] = fmaf(d1, inv, s_p[s][k0 + 1]);
      s_p[s][k0 + 2] = fmaf(d2, inv, s_p[s][k0 + 2]);
      s_p[s][k0 + 3] = fmaf(d3, inv, s_p[s][k0 + 3]);
    }
    __syncthreads();
  }

  // ---------------- Phase 3: squash + mask + output ------------------------
  if (t < KE) {
    float n2 = 0.f;
    for (int h = 0; h < HH; ++h) {
      const float v = s_high[t][h];
      n2 = fmaf(v, v, n2);
    }
    const float n  = sqrtf(n2);
    const float ne = fmaxf(n, 1e-7f);
    const float sq = ne * ne;
    float sc = sq / ((1.0f + sq) * ne);
    if (t >= ka) sc = 0.f;                 // capsule-mask multiply
    s_scale[t] = sc;
  }
  __syncthreads();
  {
    const int w = t >> 6;                  // capsule 0..7
    const int lane = t & 63;
    const float sc = s_scale[w];
    float* ob = out + (size_t)b * (KMAX * HH);
    ob[w * HH + lane]      = s_high[w][lane] * sc;
    ob[w * HH + lane + 64] = s_high[w][lane + 64] * sc;
    // capsules 8..15 are always inactive -> zero
    ob[KE * HH + t]       = 0.0f;
    ob[KE * HH + 512 + t] = 0.0f;
    if (t < KMAX) {
      float* om = out + (size_t)NB * KMAX * HH;
      om[b * KMAX + t] = (t < ka) ? 1.0f : 0.0f;
    }
  }
}

extern "C" void kernel_launch(void* const* d_in, const int* in_sizes, int n_in,
                              void* d_out, int out_size, void* d_ws, size_t ws_size,
                              hipStream_t stream) {
  const float* inputs  = (const float*)d_in[0];
  const int*   seq_len = (const int*)d_in[1];
  const float* Wm      = (const float*)d_in[2];
  const float* r_init  = (const float*)d_in[3];
  float* out           = (float*)d_out;
  hipLaunchKernelGGL(capsule_fused, dim3(NB), dim3(512), 0, stream,
                     inputs, seq_len, Wm, r_init, out);
}

// Round 4
// 345.073 us; speedup vs baseline: 2.5370x; 2.5370x over previous
//
#include <hip/hip_runtime.h>
#include <hip/hip_bf16.h>

#define NB 1024
#define SS 256
#define LL 256
#define HH 128
#define KMAX 16
#define KE 8

// ============================ Kernel 1: GEMM ================================
// low[b][s][h] = sum_l inputs[b][s][l] * W[l][h], only for row-tiles with rows < sl.
// BM=64, BN=128 (full), BK=32. 256 threads, 4x8 register tile each.
__global__ __launch_bounds__(256, 6) void gemm_low(
    const float* __restrict__ inputs, const int* __restrict__ seq_len,
    const float* __restrict__ Wm, float* __restrict__ lowbuf) {
  __shared__ __align__(16) float At[32][68];    // A chunk, transposed (k-major)
  __shared__ __align__(16) float Bs[32][128];   // W chunk, XOR-swizzled rows

  const int bid   = blockIdx.x;
  const int batch = bid >> 2;
  const int r0    = (bid & 3) * 64;
  const int sl    = seq_len[batch];
  if (r0 >= sl) return;                         // uniform early exit

  const int t  = threadIdx.x;
  const int ti = t >> 4;                        // 0..15: rows 4ti..4ti+3
  const int tj = t & 15;                        // 0..15: cols 8tj..8tj+7

  float acc[4][8];
  #pragma unroll
  for (int r = 0; r < 4; ++r)
    #pragma unroll
    for (int c = 0; c < 8; ++c) acc[r][c] = 0.f;

  const float* Ab = inputs + ((size_t)batch * SS + r0) * LL;

  for (int kc = 0; kc < LL; kc += 32) {
    // stage A: 64 rows x 32 k, transposed into At[k][r]
    #pragma unroll
    for (int m = 0; m < 2; ++m) {
      const int idx = m * 256 + t;
      const int r = idx >> 3;                   // 0..63
      const int q = idx & 7;                    // k-quad
      const float4 g = *(const float4*)(Ab + (size_t)r * LL + kc + q * 4);
      At[q * 4 + 0][r] = g.x;  At[q * 4 + 1][r] = g.y;
      At[q * 4 + 2][r] = g.z;  At[q * 4 + 3][r] = g.w;
    }
    // stage B: 32 k x 128 n, row-swizzled so k-column reads are conflict-free
    #pragma unroll
    for (int m = 0; m < 4; ++m) {
      const int idx = m * 256 + t;
      const int k = idx >> 5;                   // 0..31
      const int q = idx & 31;                   // col quad
      const float4 g = *(const float4*)(Wm + (size_t)(kc + k) * HH + q * 4);
      *(float4*)&Bs[k][(q * 4) ^ ((k & 7) << 2)] = g;
    }
    __syncthreads();

    #pragma unroll
    for (int k = 0; k < 32; ++k) {
      const float4 a4 = *(const float4*)&At[k][ti * 4];
      const int sw = (k & 7) << 2;
      const float4 b0 = *(const float4*)&Bs[k][(tj * 8) ^ sw];
      const float4 b1 = *(const float4*)&Bs[k][(tj * 8 + 4) ^ sw];
      const float av[4] = {a4.x, a4.y, a4.z, a4.w};
      const float bv[8] = {b0.x, b0.y, b0.z, b0.w, b1.x, b1.y, b1.z, b1.w};
      #pragma unroll
      for (int r = 0; r < 4; ++r)
        #pragma unroll
        for (int c = 0; c < 8; ++c)
          acc[r][c] = fmaf(av[r], bv[c], acc[r][c]);
    }
    __syncthreads();
  }

  // epilogue: write only rows < sl (rows >= sl are never read downstream)
  #pragma unroll
  for (int r = 0; r < 4; ++r) {
    const int row = r0 + ti * 4 + r;
    if (row < sl) {
      float* dst = lowbuf + ((size_t)batch * SS + row) * HH + tj * 8;
      *(float4*)dst       = make_float4(acc[r][0], acc[r][1], acc[r][2], acc[r][3]);
      *(float4*)(dst + 4) = make_float4(acc[r][4], acc[r][5], acc[r][6], acc[r][7]);
    }
  }
}

// ============================ Kernel 2: routing =============================
__global__ __launch_bounds__(1024) void routing(
    const float* __restrict__ lowbuf, const int* __restrict__ seq_len,
    const float* __restrict__ r_init, float* __restrict__ out) {
  __shared__ __align__(16) float s_low[SS][HH];     // 131072 B, XOR-swizzled
  __shared__ __align__(16) float s_p[SS][KE];       //   8192 B
  __shared__ __align__(16) float s_part[4][KE][HH]; //  16384 B
  __shared__ __align__(16) float s_high[KE][HH];    //   4096 B
  __shared__ __align__(16) float s_inv[SS];         //   1024 B
  __shared__ __align__(16) float s_scale[KE];       //     32 B  (total 160800)

  const int b = blockIdx.x;
  const int t = threadIdx.x;
  const int sl = seq_len[b];

  const int ilog = 31 - __clz(sl);
  float nh = ((sl & (sl - 1)) == 0) ? (float)ilog : log2f((float)sl);
  nh = fmaxf(1.0f, fminf(16.0f, nh));
  const int ka = (int)ceilf(nh);                    // 1..8 active capsules

  // fill s_low (swizzled), zeroing masked rows
  for (int idx = t; idx < SS * 32; idx += 1024) {
    const int s = idx >> 5, q = idx & 31;
    float4 v = make_float4(0.f, 0.f, 0.f, 0.f);
    if (s < sl) v = *(const float4*)(lowbuf + ((size_t)b * SS + s) * HH + q * 4);
    *(float4*)&s_low[s][(q * 4) ^ ((s & 7) << 2)] = v;
  }
  for (int idx = t; idx < SS * KE; idx += 1024) {
    const int s = idx >> 3, k = idx & 7;
    s_p[s][k] = r_init[((size_t)b * SS + s) * KMAX + k];
  }
  __syncthreads();

  // row inverse norms
  if (t < SS) {
    const int sw = (t & 7) << 2;
    float n2 = 0.f;
    #pragma unroll
    for (int q = 0; q < 32; ++q) {
      const float4 v = *(const float4*)&s_low[t][(q * 4) ^ sw];
      n2 = fmaf(v.x, v.x, fmaf(v.y, v.y, fmaf(v.z, v.z, fmaf(v.w, v.w, n2))));
    }
    s_inv[t] = 1.0f / fmaxf(sqrtf(n2), 1e-12f);
  }
  __syncthreads();

  // phase-b decomposition: t = g*256 + kq*128 + hg*4 + sub
  const int pb_g  = t >> 8;
  const int pb_kq = (t >> 7) & 1;
  const int pb_hg = (t >> 2) & 31;
  const int pb_sub = t & 3;
  // phase-c decomposition
  const int pc_s = t >> 2, pc_hsub = t & 3;

  for (int it = 0; it < 3; ++it) {
    // (a) masked softmax over active k
    if (t < SS) {
      const int s = t;
      float rk0 = s_p[s][0], rk1 = s_p[s][1], rk2 = s_p[s][2], rk3 = s_p[s][3];
      float rk4 = s_p[s][4], rk5 = s_p[s][5], rk6 = s_p[s][6], rk7 = s_p[s][7];
      float m = rk0;
      if (1 < ka) m = fmaxf(m, rk1);
      if (2 < ka) m = fmaxf(m, rk2);
      if (3 < ka) m = fmaxf(m, rk3);
      if (4 < ka) m = fmaxf(m, rk4);
      if (5 < ka) m = fmaxf(m, rk5);
      if (6 < ka) m = fmaxf(m, rk6);
      if (7 < ka) m = fmaxf(m, rk7);
      const float e0 = expf(rk0 - m);
      const float e1 = (1 < ka) ? expf(rk1 - m) : 0.f;
      const float e2 = (2 < ka) ? expf(rk2 - m) : 0.f;
      const float e3 = (3 < ka) ? expf(rk3 - m) : 0.f;
      const float e4 = (4 < ka) ? expf(rk4 - m) : 0.f;
      const float e5 = (5 < ka) ? expf(rk5 - m) : 0.f;
      const float e6 = (6 < ka) ? expf(rk6 - m) : 0.f;
      const float e7 = (7 < ka) ? expf(rk7 - m) : 0.f;
      const float sum = ((e0 + e1) + (e2 + e3)) + ((e4 + e5) + (e6 + e7));
      const float rs = (s < sl) ? (1.0f / sum) : 0.f;
      s_p[s][0] = e0 * rs;  s_p[s][1] = e1 * rs;
      s_p[s][2] = e2 * rs;  s_p[s][3] = e3 * rs;
      s_p[s][4] = e4 * rs;  s_p[s][5] = e5 * rs;
      s_p[s][6] = e6 * rs;  s_p[s][7] = e7 * rs;
    }
    __syncthreads();

    // (b) high[k][h] = sum_s low[s][h]*p[s][k] — p-amortized, shuffle over sub
    {
      float accf[16];
      #pragma unroll
      for (int m = 0; m < 16; ++m) accf[m] = 0.f;
      for (int i = 0; i < 16; ++i) {
        const int s = pb_g * 64 + pb_sub * 16 + i;
        const float4 v  = *(const float4*)&s_low[s][(pb_hg * 4) ^ ((s & 7) << 2)];
        const float4 p4 = *(const float4*)&s_p[s][pb_kq * 4];
        const float pv[4] = {p4.x, p4.y, p4.z, p4.w};
        #pragma unroll
        for (int kk = 0; kk < 4; ++kk) {
          accf[kk * 4 + 0] = fmaf(v.x, pv[kk], accf[kk * 4 + 0]);
          accf[kk * 4 + 1] = fmaf(v.y, pv[kk], accf[kk * 4 + 1]);
          accf[kk * 4 + 2] = fmaf(v.z, pv[kk], accf[kk * 4 + 2]);
          accf[kk * 4 + 3] = fmaf(v.w, pv[kk], accf[kk * 4 + 3]);
        }
      }
      #pragma unroll
      for (int m = 0; m < 16; ++m) accf[m] += __shfl_xor(accf[m], 1);
      #pragma unroll
      for (int m = 0; m < 16; ++m) accf[m] += __shfl_xor(accf[m], 2);
      if (pb_sub == 0) {
        #pragma unroll
        for (int kk = 0; kk < 4; ++kk)
          *(float4*)&s_part[pb_g][pb_kq * 4 + kk][pb_hg * 4] =
              make_float4(accf[kk * 4 + 0], accf[kk * 4 + 1],
                          accf[kk * 4 + 2], accf[kk * 4 + 3]);
      }
    }
    __syncthreads();
    {
      const int k = t >> 7, h = t & 127;
      s_high[k][h] = (s_part[0][k][h] + s_part[1][k][h]) +
                     (s_part[2][k][h] + s_part[3][k][h]);
    }
    __syncthreads();

    // (c) r[s][k] += inv[s] * dot(high[k], low[s]) — shuffle over hsub
    if (it < 2) {
      float d[8];
      #pragma unroll
      for (int k = 0; k < 8; ++k) d[k] = 0.f;
      const int sw = (pc_s & 7) << 2;
      #pragma unroll
      for (int q = 0; q < 8; ++q) {
        const int col = pc_hsub * 32 + q * 4;
        const float4 v = *(const float4*)&s_low[pc_s][col ^ sw];
        #pragma unroll
        for (int k = 0; k < 8; ++k) {
          const float4 hq = *(const float4*)&s_high[k][col];
          d[k] = fmaf(v.x, hq.x, fmaf(v.y, hq.y,
                 fmaf(v.z, hq.z, fmaf(v.w, hq.w, d[k]))));
        }
      }
      #pragma unroll
      for (int k = 0; k < 8; ++k) d[k] += __shfl_xor(d[k], 1);
      #pragma unroll
      for (int k = 0; k < 8; ++k) d[k] += __shfl_xor(d[k], 2);
      if (pc_hsub == 0) {
        const float inv = s_inv[pc_s];
        #pragma unroll
        for (int k = 0; k < 8; ++k)
          s_p[pc_s][k] = fmaf(d[k], inv, s_p[pc_s][k]);
      }
    }
    __syncthreads();
  }

  // squash (one wave: 8 lanes per capsule)
  if (t < 64) {
    const int k = t >> 3, part = t & 7;
    float n2 = 0.f;
    #pragma unroll
    for (int q = 0; q < 4; ++q) {
      const float4 v = *(const float4*)&s_high[k][part * 16 + q * 4];
      n2 = fmaf(v.x, v.x, fmaf(v.y, v.y, fmaf(v.z, v.z, fmaf(v.w, v.w, n2))));
    }
    n2 += __shfl_xor(n2, 1);
    n2 += __shfl_xor(n2, 2);
    n2 += __shfl_xor(n2, 4);
    if (part == 0) {
      const float n = sqrtf(n2), ne = fmaxf(n, 1e-7f), sq = ne * ne;
      float sc = sq / ((1.0f + sq) * ne);
      if (k >= ka) sc = 0.f;
      s_scale[k] = sc;
    }
  }
  __syncthreads();
  {
    const int k = t >> 7, h = t & 127;
    float* ob = out + (size_t)b * (KMAX * HH);
    ob[k * HH + h]  = s_high[k][h] * s_scale[k];
    ob[KE * HH + t] = 0.f;                       // capsules 8..15 always zero
    if (t < KMAX)
      out[(size_t)NB * KMAX * HH + (size_t)b * KMAX + t] = (t < ka) ? 1.f : 0.f;
  }
}

// ===================== Fallback: round-3 fused kernel =======================
#define LOWPAD 132
__global__ __launch_bounds__(512) void capsule_fused(
    const float* __restrict__ inputs, const int* __restrict__ seq_len,
    const float* __restrict__ Wm, const float* __restrict__ r_init,
    float* __restrict__ out) {
  __shared__ __align__(16) float s_low[SS][LOWPAD];
  __shared__ __align__(16) float s_p[SS][KE];
  __shared__ __align__(16) float s_part[2][KE][HH];
  __shared__ __align__(16) float s_high[KE][HH];
  __shared__ __align__(16) float s_inv[SS];
  __shared__ __align__(16) float s_scale[KE];
  const int b = blockIdx.x, t = threadIdx.x, sl = seq_len[b];
  const int ilog = 31 - __clz(sl);
  float nh = ((sl & (sl - 1)) == 0) ? (float)ilog : log2f((float)sl);
  nh = fmaxf(1.0f, fminf(16.0f, nh));
  const int ka = (int)ceilf(nh);
  {
    const int hg = t & 15, h0 = hg * 8, rg = t >> 4;
    const float* inb = inputs + (size_t)b * SS * LL;
    for (int sweep = 0; sweep < 8; ++sweep) {
      const int s = sweep * 32 + rg;
      float a0=0.f,a1=0.f,a2=0.f,a3=0.f,a4=0.f,a5=0.f,a6=0.f,a7=0.f;
      if (s < sl) {
        const float* inp = inb + (size_t)s * LL;
        for (int l = 0; l < LL; l += 4) {
          const float4 iv = *(const float4*)(inp + l);
          #pragma unroll
          for (int d = 0; d < 4; ++d) {
            const float f = (d==0)?iv.x:(d==1)?iv.y:(d==2)?iv.z:iv.w;
            const float* wp = Wm + (size_t)(l + d) * HH + h0;
            const float4 wa = *(const float4*)(wp);
            const float4 wb = *(const float4*)(wp + 4);
            a0=fmaf(f,wa.x,a0); a1=fmaf(f,wa.y,a1); a2=fmaf(f,wa.z,a2); a3=fmaf(f,wa.w,a3);
            a4=fmaf(f,wb.x,a4); a5=fmaf(f,wb.y,a5); a6=fmaf(f,wb.z,a6); a7=fmaf(f,wb.w,a7);
          }
        }
      }
      s_low[s][h0+0]=a0; s_low[s][h0+1]=a1; s_low[s][h0+2]=a2; s_low[s][h0+3]=a3;
      s_low[s][h0+4]=a4; s_low[s][h0+5]=a5; s_low[s][h0+6]=a6; s_low[s][h0+7]=a7;
    }
  }
  for (int idx = t; idx < SS * KE; idx += 512) {
    const int s = idx >> 3, k = idx & 7;
    s_p[s][k] = r_init[((size_t)b * SS + s) * KMAX + k];
  }
  __syncthreads();
  if (t < SS) {
    float n2 = 0.f;
    for (int h = 0; h < HH; ++h) { const float v = s_low[t][h]; n2 = fmaf(v, v, n2); }
    s_inv[t] = 1.0f / fmaxf(sqrtf(n2), 1e-12f);
  }
  __syncthreads();
  for (int it = 0; it < 3; ++it) {
    if (t < SS) {
      const int s = t;
      float rk0=s_p[s][0],rk1=s_p[s][1],rk2=s_p[s][2],rk3=s_p[s][3];
      float rk4=s_p[s][4],rk5=s_p[s][5],rk6=s_p[s][6],rk7=s_p[s][7];
      float m = rk0;
      if (1<ka) m=fmaxf(m,rk1); if (2<ka) m=fmaxf(m,rk2); if (3<ka) m=fmaxf(m,rk3);
      if (4<ka) m=fmaxf(m,rk4); if (5<ka) m=fmaxf(m,rk5); if (6<ka) m=fmaxf(m,rk6);
      if (7<ka) m=fmaxf(m,rk7);
      const float e0=expf(rk0-m);
      const float e1=(1<ka)?expf(rk1-m):0.f, e2=(2<ka)?expf(rk2-m):0.f;
      const float e3=(3<ka)?expf(rk3-m):0.f, e4=(4<ka)?expf(rk4-m):0.f;
      const float e5=(5<ka)?expf(rk5-m):0.f, e6=(6<ka)?expf(rk6-m):0.f;
      const float e7=(7<ka)?expf(rk7-m):0.f;
      const float sum=((e0+e1)+(e2+e3))+((e4+e5)+(e6+e7));
      const float rs=(s<sl)?(1.0f/sum):0.f;
      s_p[s][0]=e0*rs; s_p[s][1]=e1*rs; s_p[s][2]=e2*rs; s_p[s][3]=e3*rs;
      s_p[s][4]=e4*rs; s_p[s][5]=e5*rs; s_p[s][6]=e6*rs; s_p[s][7]=e7*rs;
    }
    __syncthreads();
    {
      const int g=t>>8, w4=(t>>6)&3, k=(t&63)>>3, hg=t&7, h0=w4*32+hg*4;
      float a0=0.f,a1=0.f,a2=0.f,a3=0.f;
      const int sbase=g*128;
      for (int i=0;i<128;++i) {
        const int s=sbase+i;
        const float4 v=*(const float4*)&s_low[s][h0];
        const float p=s_p[s][k];
        a0=fmaf(v.x,p,a0); a1=fmaf(v.y,p,a1); a2=fmaf(v.z,p,a2); a3=fmaf(v.w,p,a3);
      }
      s_part[g][k][h0+0]=a0; s_part[g][k][h0+1]=a1;
      s_part[g][k][h0+2]=a2; s_part[g][k][h0+3]=a3;
    }
    __syncthreads();
    for (int idx=t; idx<KE*HH; idx+=512) {
      const int k=idx>>7, h=idx&127;
      s_high[k][h]=s_part[0][k][h]+s_part[1][k][h];
    }
    __syncthreads();
    if (it < 2) {
      const int s=t&255, k0=(t>>8)<<2;
      float d0=0.f,d1=0.f,d2=0.f,d3=0.f;
      for (int h=0;h<HH;h+=4) {
        const float4 v=*(const float4*)&s_low[s][h];
        const float4 q0=*(const float4*)&s_high[k0+0][h];
        const float4 q1=*(const float4*)&s_high[k0+1][h];
        const float4 q2=*(const float4*)&s_high[k0+2][h];
        const float4 q3=*(const float4*)&s_high[k0+3][h];
        d0=fmaf(v.x,q0.x,fmaf(v.y,q0.y,fmaf(v.z,q0.z,fmaf(v.w,q0.w,d0))));
        d1=fmaf(v.x,q1.x,fmaf(v.y,q1.y,fmaf(v.z,q1.z,fmaf(v.w,q1.w,d1))));
        d2=fmaf(v.x,q2.x,fmaf(v.y,q2.y,fmaf(v.z,q2.z,fmaf(v.w,q2.w,d2))));
        d3=fmaf(v.x,q3.x,fmaf(v.y,q3.y,fmaf(v.z,q3.z,fmaf(v.w,q3.w,d3))));
      }
      const float inv=s_inv[s];
      s_p[s][k0+0]=fmaf(d0,inv,s_p[s][k0+0]);
      s_p[s][k0+1]=fmaf(d1,inv,s_p[s][k0+1]);
      s_p[s][k0+2]=fmaf(d2,inv,s_p[s][k0+2]);
      s_p[s][k0+3]=fmaf(d3,inv,s_p[s][k0+3]);
    }
    __syncthreads();
  }
  if (t < KE) {
    float n2=0.f;
    for (int h=0;h<HH;++h){ const float v=s_high[t][h]; n2=fmaf(v,v,n2); }
    const float n=sqrtf(n2), ne=fmaxf(n,1e-7f), sq=ne*ne;
    float sc=sq/((1.0f+sq)*ne);
    if (t>=ka) sc=0.f;
    s_scale[t]=sc;
  }
  __syncthreads();
  {
    const int w=t>>6, lane=t&63;
    const float sc=s_scale[w];
    float* ob=out+(size_t)b*(KMAX*HH);
    ob[w*HH+lane]=s_high[w][lane]*sc;
    ob[w*HH+lane+64]=s_high[w][lane+64]*sc;
    ob[KE*HH+t]=0.0f; ob[KE*HH+512+t]=0.0f;
    if (t<KMAX) {
      float* om=out+(size_t)NB*KMAX*HH;
      om[b*KMAX+t]=(t<ka)?1.0f:0.0f;
    }
  }
}

extern "C" void kernel_launch(void* const* d_in, const int* in_sizes, int n_in,
                              void* d_out, int out_size, void* d_ws, size_t ws_size,
                              hipStream_t stream) {
  const float* inputs  = (const float*)d_in[0];
  const int*   seq_len = (const int*)d_in[1];
  const float* Wm      = (const float*)d_in[2];
  const float* r_init  = (const float*)d_in[3];
  float* out           = (float*)d_out;
  const size_t need = (size_t)NB * SS * HH * sizeof(float);   // 128 MB
  if (ws_size >= need) {
    float* lowbuf = (float*)d_ws;
    hipLaunchKernelGGL(gemm_low, dim3(NB * 4), dim3(256), 0, stream,
                       inputs, seq_len, Wm, lowbuf);
    hipLaunchKernelGGL(routing, dim3(NB), dim3(1024), 0, stream,
                       lowbuf, seq_len, r_init, out);
  } else {
    hipLaunchKernelGGL(capsule_fused, dim3(NB), dim3(512), 0, stream,
                       inputs, seq_len, Wm, r_init, out);
  }
}

// Round 5
// 299.452 us; speedup vs baseline: 2.9235x; 1.1523x over previous
//
#include <hip/hip_runtime.h>
#include <hip/hip_bf16.h>

#define NB 1024
#define SS 256
#define LL 256
#define HH 128
#define KMAX 16
#define KE 8

typedef __attribute__((ext_vector_type(8))) short bf16x8;
typedef __attribute__((ext_vector_type(4))) float f32x4;
typedef unsigned short u16;
typedef unsigned int u32;

__device__ __forceinline__ void split_bf16(float a, u16& hi, u16& lo) {
  u32 u = __float_as_uint(a);
  u32 hb = (u + 0x8000u) & 0xFFFF0000u;      // RTN-ish bf16 hi
  float lf = a - __uint_as_float(hb);        // exact residual
  hi = (u16)(hb >> 16);
  lo = (u16)(__float_as_uint(lf) >> 16);     // truncated bf16 lo
}

// ---- prep: W[l][h] -> Wt_hi[h][l], Wt_lo[h][l] (bf16 split, transposed) ----
__global__ __launch_bounds__(256) void prep_w(
    const float* __restrict__ Wm, u16* __restrict__ wt_hi, u16* __restrict__ wt_lo) {
  const int id = blockIdx.x * 256 + threadIdx.x;   // 32768
  const int h = id & 127, l = id >> 7;
  const float a = Wm[(size_t)l * HH + h];
  u16 hi, lo;
  split_bf16(a, hi, lo);
  wt_hi[h * LL + l] = hi;
  wt_lo[h * LL + l] = lo;
}

// ============== Kernel 1: MFMA GEMM, split-bf16 fp32 emulation ==============
#define BM 128
#define BK 32
#define APAD 40   // ushorts/row = 80 B = 20 words: b128 reads/writes at bank floor

__global__ __launch_bounds__(256, 3) void gemm_mfma(
    const float* __restrict__ inputs, const int* __restrict__ seq_len,
    const u16* __restrict__ wt_hi, const u16* __restrict__ wt_lo,
    float* __restrict__ lowbuf) {
  __shared__ u16 Ahi[BM][APAD], Alo[BM][APAD];   // 10240 B each
  __shared__ u16 Bhi[HH][APAD], Blo[HH][APAD];   // 10240 B each (40960 total)

  const int bid = blockIdx.x;
  const int batch = bid >> 1;
  const int r0 = (bid & 1) * BM;
  const int sl = seq_len[batch];
  if (r0 >= sl) return;

  const int t = threadIdx.x;
  const int w = t >> 6;          // wave 0..3 -> rows w*32 .. +31
  const int l = t & 63;
  const int lr = l & 15;         // A-row / B-col / D-col in tile
  const int lk = l >> 4;         // k-octet 0..3

  f32x4 acc[2][8];
  #pragma unroll
  for (int mt = 0; mt < 2; ++mt)
    #pragma unroll
    for (int nt = 0; nt < 8; ++nt) acc[mt][nt] = (f32x4){0.f, 0.f, 0.f, 0.f};

  const float* Ab = inputs + ((size_t)batch * SS + r0) * LL;
  const int bh = t >> 1, be = t & 1;    // B-staging coords

  for (int kc = 0; kc < LL; kc += BK) {
    // ---- stage A: 128x32 f32 -> split bf16 (4 float4 per thread) ----
    #pragma unroll
    for (int m = 0; m < 4; ++m) {
      const int g = m * 256 + t;
      const int row = g >> 3, q = g & 7;
      const float4 v = *(const float4*)(Ab + (size_t)row * LL + kc + q * 4);
      u16 h0,h1,h2,h3, l0,l1,l2,l3;
      split_bf16(v.x, h0, l0); split_bf16(v.y, h1, l1);
      split_bf16(v.z, h2, l2); split_bf16(v.w, h3, l3);
      uint2 hp, lp;
      hp.x = (u32)h0 | ((u32)h1 << 16);  hp.y = (u32)h2 | ((u32)h3 << 16);
      lp.x = (u32)l0 | ((u32)l1 << 16);  lp.y = (u32)l2 | ((u32)l3 << 16);
      *(uint2*)&Ahi[row][q * 4] = hp;
      *(uint2*)&Alo[row][q * 4] = lp;
    }
    // ---- stage B: copy pre-split Wt slices (16B chunks) ----
    {
      const u16* sh = wt_hi + (size_t)bh * LL + kc + be * 16;
      const u16* sv = wt_lo + (size_t)bh * LL + kc + be * 16;
      *(uint4*)&Bhi[bh][be * 16]     = *(const uint4*)(sh);
      *(uint4*)&Bhi[bh][be * 16 + 8] = *(const uint4*)(sh + 8);
      *(uint4*)&Blo[bh][be * 16]     = *(const uint4*)(sv);
      *(uint4*)&Blo[bh][be * 16 + 8] = *(const uint4*)(sv + 8);
    }
    __syncthreads();

    bf16x8 ah[2], al[2];
    #pragma unroll
    for (int mt = 0; mt < 2; ++mt) {
      const int row = w * 32 + mt * 16 + lr;
      ah[mt] = *(const bf16x8*)&Ahi[row][lk * 8];
      al[mt] = *(const bf16x8*)&Alo[row][lk * 8];
    }
    #pragma unroll
    for (int nt = 0; nt < 8; ++nt) {
      const int col = nt * 16 + lr;
      const bf16x8 bhf = *(const bf16x8*)&Bhi[col][lk * 8];
      const bf16x8 blf = *(const bf16x8*)&Blo[col][lk * 8];
      #pragma unroll
      for (int mt = 0; mt < 2; ++mt) {
        acc[mt][nt] = __builtin_amdgcn_mfma_f32_16x16x32_bf16(ah[mt], bhf, acc[mt][nt], 0, 0, 0);
        acc[mt][nt] = __builtin_amdgcn_mfma_f32_16x16x32_bf16(ah[mt], blf, acc[mt][nt], 0, 0, 0);
        acc[mt][nt] = __builtin_amdgcn_mfma_f32_16x16x32_bf16(al[mt], bhf, acc[mt][nt], 0, 0, 0);
      }
    }
    __syncthreads();
  }

  // epilogue: D[row=(l>>4)*4+j][col=l&15] per tile
  #pragma unroll
  for (int mt = 0; mt < 2; ++mt)
    #pragma unroll
    for (int j = 0; j < 4; ++j) {
      const int row = r0 + w * 32 + mt * 16 + lk * 4 + j;
      if (row < sl) {
        float* dst = lowbuf + ((size_t)batch * SS + row) * HH;
        #pragma unroll
        for (int nt = 0; nt < 8; ++nt) dst[nt * 16 + lr] = acc[mt][nt][j];
      }
    }
}

// ============== Fallback fp32 GEMM (round-4, ws-limited path) ==============
__global__ __launch_bounds__(256, 6) void gemm_low(
    const float* __restrict__ inputs, const int* __restrict__ seq_len,
    const float* __restrict__ Wm, float* __restrict__ lowbuf) {
  __shared__ __align__(16) float At[32][68];
  __shared__ __align__(16) float Bs[32][128];
  const int bid = blockIdx.x, batch = bid >> 2, r0 = (bid & 3) * 64;
  const int sl = seq_len[batch];
  if (r0 >= sl) return;
  const int t = threadIdx.x, ti = t >> 4, tj = t & 15;
  float acc[4][8];
  #pragma unroll
  for (int r = 0; r < 4; ++r)
    #pragma unroll
    for (int c = 0; c < 8; ++c) acc[r][c] = 0.f;
  const float* Ab = inputs + ((size_t)batch * SS + r0) * LL;
  for (int kc = 0; kc < LL; kc += 32) {
    #pragma unroll
    for (int m = 0; m < 2; ++m) {
      const int idx = m * 256 + t, r = idx >> 3, q = idx & 7;
      const float4 g = *(const float4*)(Ab + (size_t)r * LL + kc + q * 4);
      At[q*4+0][r] = g.x; At[q*4+1][r] = g.y; At[q*4+2][r] = g.z; At[q*4+3][r] = g.w;
    }
    #pragma unroll
    for (int m = 0; m < 4; ++m) {
      const int idx = m * 256 + t, k = idx >> 5, q = idx & 31;
      const float4 g = *(const float4*)(Wm + (size_t)(kc + k) * HH + q * 4);
      *(float4*)&Bs[k][(q * 4) ^ ((k & 7) << 2)] = g;
    }
    __syncthreads();
    #pragma unroll
    for (int k = 0; k < 32; ++k) {
      const float4 a4 = *(const float4*)&At[k][ti * 4];
      const int sw = (k & 7) << 2;
      const float4 b0 = *(const float4*)&Bs[k][(tj * 8) ^ sw];
      const float4 b1 = *(const float4*)&Bs[k][(tj * 8 + 4) ^ sw];
      const float av[4] = {a4.x, a4.y, a4.z, a4.w};
      const float bv[8] = {b0.x, b0.y, b0.z, b0.w, b1.x, b1.y, b1.z, b1.w};
      #pragma unroll
      for (int r = 0; r < 4; ++r)
        #pragma unroll
        for (int c = 0; c < 8; ++c) acc[r][c] = fmaf(av[r], bv[c], acc[r][c]);
    }
    __syncthreads();
  }
  #pragma unroll
  for (int r = 0; r < 4; ++r) {
    const int row = r0 + ti * 4 + r;
    if (row < sl) {
      float* dst = lowbuf + ((size_t)batch * SS + row) * HH + tj * 8;
      *(float4*)dst       = make_float4(acc[r][0], acc[r][1], acc[r][2], acc[r][3]);
      *(float4*)(dst + 4) = make_float4(acc[r][4], acc[r][5], acc[r][6], acc[r][7]);
    }
  }
}

// ===================== Kernel 2: routing (bank-floor access) =====================
__global__ __launch_bounds__(1024) void routing2(
    const float* __restrict__ lowbuf, const int* __restrict__ seq_len,
    const float* __restrict__ r_init, float* __restrict__ out) {
  __shared__ __align__(16) float s_low[SS][HH];      // 131072
  __shared__ __align__(16) float s_p[SS][KE];        //   8192
  __shared__ __align__(16) float s_part[4][KE][HH];  //  16384
  __shared__ __align__(16) float s_high[KE][HH];     //   4096
  __shared__ __align__(16) float s_inv[SS];          //   1024
  __shared__ __align__(16) float s_scale[KE];        //     32  -> 160800 B

  const int b = blockIdx.x, t = threadIdx.x, sl = seq_len[b];
  const int w = t >> 6, l = t & 63, half = l >> 5, l31 = l & 31;

  const int ilog = 31 - __clz(sl);
  float nh = ((sl & (sl - 1)) == 0) ? (float)ilog : log2f((float)sl);
  nh = fmaxf(1.0f, fminf(16.0f, nh));
  const int ka = (int)ceilf(nh);

  // fill s_low (masked rows zeroed) + s_p
  #pragma unroll
  for (int m = 0; m < 8; ++m) {
    const int idx = m * 1024 + t;
    const int s = idx >> 5, q = idx & 31;
    float4 v = make_float4(0.f, 0.f, 0.f, 0.f);
    if (s < sl) v = *(const float4*)(lowbuf + ((size_t)b * SS + s) * HH + q * 4);
    *(float4*)&s_low[s][q * 4] = v;
  }
  #pragma unroll
  for (int m = 0; m < 2; ++m) {
    const int idx = m * 1024 + t;
    const int s = idx >> 3, k = idx & 7;
    s_p[s][k] = r_init[((size_t)b * SS + s) * KMAX + k];
  }
  __syncthreads();

  // row inverse norms: wave per 2 rows, lane=col-quad, butterfly reduce
  #pragma unroll
  for (int i8 = 0; i8 < 8; ++i8) {
    const int s = w * 16 + i8 * 2 + half;
    const float4 v = *(const float4*)&s_low[s][l31 * 4];
    float n2 = fmaf(v.x, v.x, fmaf(v.y, v.y, fmaf(v.z, v.z, v.w * v.w)));
    n2 += __shfl_xor(n2, 1, 64);  n2 += __shfl_xor(n2, 2, 64);
    n2 += __shfl_xor(n2, 4, 64);  n2 += __shfl_xor(n2, 8, 64);
    n2 += __shfl_xor(n2, 16, 64);
    if (l31 == 0) s_inv[s] = 1.0f / fmaxf(sqrtf(n2), 1e-12f);
  }
  __syncthreads();

  for (int it = 0; it < 3; ++it) {
    // (a) masked softmax over active k
    if (t < SS) {
      const int s = t;
      const float4 ra = *(const float4*)&s_p[s][0];
      const float4 rb = *(const float4*)&s_p[s][4];
      float m = ra.x;
      if (1 < ka) m = fmaxf(m, ra.y);
      if (2 < ka) m = fmaxf(m, ra.z);
      if (3 < ka) m = fmaxf(m, ra.w);
      if (4 < ka) m = fmaxf(m, rb.x);
      if (5 < ka) m = fmaxf(m, rb.y);
      if (6 < ka) m = fmaxf(m, rb.z);
      if (7 < ka) m = fmaxf(m, rb.w);
      const float e0 = expf(ra.x - m);
      const float e1 = (1 < ka) ? expf(ra.y - m) : 0.f;
      const float e2 = (2 < ka) ? expf(ra.z - m) : 0.f;
      const float e3 = (3 < ka) ? expf(ra.w - m) : 0.f;
      const float e4 = (4 < ka) ? expf(rb.x - m) : 0.f;
      const float e5 = (5 < ka) ? expf(rb.y - m) : 0.f;
      const float e6 = (6 < ka) ? expf(rb.z - m) : 0.f;
      const float e7 = (7 < ka) ? expf(rb.w - m) : 0.f;
      const float sum = ((e0 + e1) + (e2 + e3)) + ((e4 + e5) + (e6 + e7));
      const float rs = (s < sl) ? (1.0f / sum) : 0.f;
      *(float4*)&s_p[s][0] = make_float4(e0 * rs, e1 * rs, e2 * rs, e3 * rs);
      *(float4*)&s_p[s][4] = make_float4(e4 * rs, e5 * rs, e6 * rs, e7 * rs);
    }
    __syncthreads();

    // (b) high partials: waves 0..7, wave=(kq,g), k-amortized x4
    if (w < 8) {
      const int kq = w & 1, g = w >> 1;
      f32x4 a0 = (f32x4){0,0,0,0}, a1 = a0, a2 = a0, a3 = a0;
      for (int i = 0; i < 32; ++i) {
        const int s = g * 64 + half * 32 + i;
        const float4 v = *(const float4*)&s_low[s][l31 * 4];
        const float4 p = *(const float4*)&s_p[s][kq * 4];
        a0.x = fmaf(v.x, p.x, a0.x); a0.y = fmaf(v.y, p.x, a0.y);
        a0.z = fmaf(v.z, p.x, a0.z); a0.w = fmaf(v.w, p.x, a0.w);
        a1.x = fmaf(v.x, p.y, a1.x); a1.y = fmaf(v.y, p.y, a1.y);
        a1.z = fmaf(v.z, p.y, a1.z); a1.w = fmaf(v.w, p.y, a1.w);
        a2.x = fmaf(v.x, p.z, a2.x); a2.y = fmaf(v.y, p.z, a2.y);
        a2.z = fmaf(v.z, p.z, a2.z); a2.w = fmaf(v.w, p.z, a2.w);
        a3.x = fmaf(v.x, p.w, a3.x); a3.y = fmaf(v.y, p.w, a3.y);
        a3.z = fmaf(v.z, p.w, a3.z); a3.w = fmaf(v.w, p.w, a3.w);
      }
      #pragma unroll
      for (int c = 0; c < 4; ++c) {
        a0[c] += __shfl_xor(a0[c], 32, 64);
        a1[c] += __shfl_xor(a1[c], 32, 64);
        a2[c] += __shfl_xor(a2[c], 32, 64);
        a3[c] += __shfl_xor(a3[c], 32, 64);
      }
      if (half == 0) {
        *(f32x4*)&s_part[g][kq * 4 + 0][l31 * 4] = a0;
        *(f32x4*)&s_part[g][kq * 4 + 1][l31 * 4] = a1;
        *(f32x4*)&s_part[g][kq * 4 + 2][l31 * 4] = a2;
        *(f32x4*)&s_part[g][kq * 4 + 3][l31 * 4] = a3;
      }
    }
    __syncthreads();
    {
      const int k = t >> 7, h = t & 127;
      s_high[k][h] = (s_part[0][k][h] + s_part[1][k][h]) +
                     (s_part[2][k][h] + s_part[3][k][h]);
    }
    __syncthreads();

    // (c) r[s][k] += inv[s] * dot(high[k], low[s]) — hoisted high, butterfly
    if (it < 2) {
      float4 hq[8];
      #pragma unroll
      for (int k = 0; k < 8; ++k) hq[k] = *(const float4*)&s_high[k][l31 * 4];
      #pragma unroll
      for (int i8 = 0; i8 < 8; ++i8) {
        const int s = w * 16 + i8 * 2 + half;
        const float4 v = *(const float4*)&s_low[s][l31 * 4];
        float d[8];
        #pragma unroll
        for (int k = 0; k < 8; ++k)
          d[k] = fmaf(v.x, hq[k].x, fmaf(v.y, hq[k].y,
                 fmaf(v.z, hq[k].z, v.w * hq[k].w)));
        #pragma unroll
        for (int k = 0; k < 8; ++k) {
          d[k] += __shfl_xor(d[k], 1, 64);  d[k] += __shfl_xor(d[k], 2, 64);
          d[k] += __shfl_xor(d[k], 4, 64);  d[k] += __shfl_xor(d[k], 8, 64);
          d[k] += __shfl_xor(d[k], 16, 64);
        }
        if (l31 == 0) {
          const float inv = s_inv[s];
          float4 p0 = *(const float4*)&s_p[s][0];
          float4 p1 = *(const float4*)&s_p[s][4];
          p0.x = fmaf(d[0], inv, p0.x); p0.y = fmaf(d[1], inv, p0.y);
          p0.z = fmaf(d[2], inv, p0.z); p0.w = fmaf(d[3], inv, p0.w);
          p1.x = fmaf(d[4], inv, p1.x); p1.y = fmaf(d[5], inv, p1.y);
          p1.z = fmaf(d[6], inv, p1.z); p1.w = fmaf(d[7], inv, p1.w);
          *(float4*)&s_p[s][0] = p0;
          *(float4*)&s_p[s][4] = p1;
        }
      }
    }
    __syncthreads();
  }

  // squash
  if (t < 64) {
    const int k = t >> 3, part = t & 7;
    float n2 = 0.f;
    #pragma unroll
    for (int q = 0; q < 4; ++q) {
      const float4 v = *(const float4*)&s_high[k][part * 16 + q * 4];
      n2 = fmaf(v.x, v.x, fmaf(v.y, v.y, fmaf(v.z, v.z, fmaf(v.w, v.w, n2))));
    }
    n2 += __shfl_xor(n2, 1, 64);
    n2 += __shfl_xor(n2, 2, 64);
    n2 += __shfl_xor(n2, 4, 64);
    if (part == 0) {
      const float n = sqrtf(n2), ne = fmaxf(n, 1e-7f), sq = ne * ne;
      float sc = sq / ((1.0f + sq) * ne);
      if (k >= ka) sc = 0.f;
      s_scale[k] = sc;
    }
  }
  __syncthreads();
  {
    const int k = t >> 7, h = t & 127;
    float* ob = out + (size_t)b * (KMAX * HH);
    ob[k * HH + h]  = s_high[k][h] * s_scale[k];
    ob[KE * HH + t] = 0.f;
    if (t < KMAX)
      out[(size_t)NB * KMAX * HH + (size_t)b * KMAX + t] = (t < ka) ? 1.f : 0.f;
  }
}

// ===================== Fallback: round-3 fused kernel =======================
#define LOWPAD 132
__global__ __launch_bounds__(512) void capsule_fused(
    const float* __restrict__ inputs, const int* __restrict__ seq_len,
    const float* __restrict__ Wm, const float* __restrict__ r_init,
    float* __restrict__ out) {
  __shared__ __align__(16) float s_low[SS][LOWPAD];
  __shared__ __align__(16) float s_p[SS][KE];
  __shared__ __align__(16) float s_part[2][KE][HH];
  __shared__ __align__(16) float s_high[KE][HH];
  __shared__ __align__(16) float s_inv[SS];
  __shared__ __align__(16) float s_scale[KE];
  const int b = blockIdx.x, t = threadIdx.x, sl = seq_len[b];
  const int ilog = 31 - __clz(sl);
  float nh = ((sl & (sl - 1)) == 0) ? (float)ilog : log2f((float)sl);
  nh = fmaxf(1.0f, fminf(16.0f, nh));
  const int ka = (int)ceilf(nh);
  {
    const int hg = t & 15, h0 = hg * 8, rg = t >> 4;
    const float* inb = inputs + (size_t)b * SS * LL;
    for (int sweep = 0; sweep < 8; ++sweep) {
      const int s = sweep * 32 + rg;
      float a0=0.f,a1=0.f,a2=0.f,a3=0.f,a4=0.f,a5=0.f,a6=0.f,a7=0.f;
      if (s < sl) {
        const float* inp = inb + (size_t)s * LL;
        for (int ll = 0; ll < LL; ll += 4) {
          const float4 iv = *(const float4*)(inp + ll);
          #pragma unroll
          for (int d = 0; d < 4; ++d) {
            const float f = (d==0)?iv.x:(d==1)?iv.y:(d==2)?iv.z:iv.w;
            const float* wp = Wm + (size_t)(ll + d) * HH + h0;
            const float4 wa = *(const float4*)(wp);
            const float4 wb = *(const float4*)(wp + 4);
            a0=fmaf(f,wa.x,a0); a1=fmaf(f,wa.y,a1); a2=fmaf(f,wa.z,a2); a3=fmaf(f,wa.w,a3);
            a4=fmaf(f,wb.x,a4); a5=fmaf(f,wb.y,a5); a6=fmaf(f,wb.z,a6); a7=fmaf(f,wb.w,a7);
          }
        }
      }
      s_low[s][h0+0]=a0; s_low[s][h0+1]=a1; s_low[s][h0+2]=a2; s_low[s][h0+3]=a3;
      s_low[s][h0+4]=a4; s_low[s][h0+5]=a5; s_low[s][h0+6]=a6; s_low[s][h0+7]=a7;
    }
  }
  for (int idx = t; idx < SS * KE; idx += 512) {
    const int s = idx >> 3, k = idx & 7;
    s_p[s][k] = r_init[((size_t)b * SS + s) * KMAX + k];
  }
  __syncthreads();
  if (t < SS) {
    float n2 = 0.f;
    for (int h = 0; h < HH; ++h) { const float v = s_low[t][h]; n2 = fmaf(v, v, n2); }
    s_inv[t] = 1.0f / fmaxf(sqrtf(n2), 1e-12f);
  }
  __syncthreads();
  for (int it = 0; it < 3; ++it) {
    if (t < SS) {
      const int s = t;
      float rk0=s_p[s][0],rk1=s_p[s][1],rk2=s_p[s][2],rk3=s_p[s][3];
      float rk4=s_p[s][4],rk5=s_p[s][5],rk6=s_p[s][6],rk7=s_p[s][7];
      float m = rk0;
      if (1<ka) m=fmaxf(m,rk1); if (2<ka) m=fmaxf(m,rk2); if (3<ka) m=fmaxf(m,rk3);
      if (4<ka) m=fmaxf(m,rk4); if (5<ka) m=fmaxf(m,rk5); if (6<ka) m=fmaxf(m,rk6);
      if (7<ka) m=fmaxf(m,rk7);
      const float e0=expf(rk0-m);
      const float e1=(1<ka)?expf(rk1-m):0.f, e2=(2<ka)?expf(rk2-m):0.f;
      const float e3=(3<ka)?expf(rk3-m):0.f, e4=(4<ka)?expf(rk4-m):0.f;
      const float e5=(5<ka)?expf(rk5-m):0.f, e6=(6<ka)?expf(rk6-m):0.f;
      const float e7=(7<ka)?expf(rk7-m):0.f;
      const float sum=((e0+e1)+(e2+e3))+((e4+e5)+(e6+e7));
      const float rs=(s<sl)?(1.0f/sum):0.f;
      s_p[s][0]=e0*rs; s_p[s][1]=e1*rs; s_p[s][2]=e2*rs; s_p[s][3]=e3*rs;
      s_p[s][4]=e4*rs; s_p[s][5]=e5*rs; s_p[s][6]=e6*rs; s_p[s][7]=e7*rs;
    }
    __syncthreads();
    {
      const int g=t>>8, w4=(t>>6)&3, k=(t&63)>>3, hg=t&7, h0=w4*32+hg*4;
      float a0=0.f,a1=0.f,a2=0.f,a3=0.f;
      const int sbase=g*128;
      for (int i=0;i<128;++i) {
        const int s=sbase+i;
        const float4 v=*(const float4*)&s_low[s][h0];
        const float p=s_p[s][k];
        a0=fmaf(v.x,p,a0); a1=fmaf(v.y,p,a1); a2=fmaf(v.z,p,a2); a3=fmaf(v.w,p,a3);
      }
      s_part[g][k][h0+0]=a0; s_part[g][k][h0+1]=a1;
      s_part[g][k][h0+2]=a2; s_part[g][k][h0+3]=a3;
    }
    __syncthreads();
    for (int idx=t; idx<KE*HH; idx+=512) {
      const int k=idx>>7, h=idx&127;
      s_high[k][h]=s_part[0][k][h]+s_part[1][k][h];
    }
    __syncthreads();
    if (it < 2) {
      const int s=t&255, k0=(t>>8)<<2;
      float d0=0.f,d1=0.f,d2=0.f,d3=0.f;
      for (int h=0;h<HH;h+=4) {
        const float4 v=*(const float4*)&s_low[s][h];
        const float4 q0=*(const float4*)&s_high[k0+0][h];
        const float4 q1=*(const float4*)&s_high[k0+1][h];
        const float4 q2=*(const float4*)&s_high[k0+2][h];
        const float4 q3=*(const float4*)&s_high[k0+3][h];
        d0=fmaf(v.x,q0.x,fmaf(v.y,q0.y,fmaf(v.z,q0.z,fmaf(v.w,q0.w,d0))));
        d1=fmaf(v.x,q1.x,fmaf(v.y,q1.y,fmaf(v.z,q1.z,fmaf(v.w,q1.w,d1))));
        d2=fmaf(v.x,q2.x,fmaf(v.y,q2.y,fmaf(v.z,q2.z,fmaf(v.w,q2.w,d2))));
        d3=fmaf(v.x,q3.x,fmaf(v.y,q3.y,fmaf(v.z,q3.z,fmaf(v.w,q3.w,d3))));
      }
      const float inv=s_inv[s];
      s_p[s][k0+0]=fmaf(d0,inv,s_p[s][k0+0]);
      s_p[s][k0+1]=fmaf(d1,inv,s_p[s][k0+1]);
      s_p[s][k0+2]=fmaf(d2,inv,s_p[s][k0+2]);
      s_p[s][k0+3]=fmaf(d3,inv,s_p[s][k0+3]);
    }
    __syncthreads();
  }
  if (t < KE) {
    float n2=0.f;
    for (int h=0;h<HH;++h){ const float v=s_high[t][h]; n2=fmaf(v,v,n2); }
    const float n=sqrtf(n2), ne=fmaxf(n,1e-7f), sq=ne*ne;
    float sc=sq/((1.0f+sq)*ne);
    if (t>=ka) sc=0.f;
    s_scale[t]=sc;
  }
  __syncthreads();
  {
    const int w2=t>>6, lane=t&63;
    const float sc=s_scale[w2];
    float* ob=out+(size_t)b*(KMAX*HH);
    ob[w2*HH+lane]=s_high[w2][lane]*sc;
    ob[w2*HH+lane+64]=s_high[w2][lane+64]*sc;
    ob[KE*HH+t]=0.0f; ob[KE*HH+512+t]=0.0f;
    if (t<KMAX) {
      float* om=out+(size_t)NB*KMAX*HH;
      om[b*KMAX+t]=(t<ka)?1.0f:0.0f;
    }
  }
}

extern "C" void kernel_launch(void* const* d_in, const int* in_sizes, int n_in,
                              void* d_out, int out_size, void* d_ws, size_t ws_size,
                              hipStream_t stream) {
  const float* inputs  = (const float*)d_in[0];
  const int*   seq_len = (const int*)d_in[1];
  const float* Wm      = (const float*)d_in[2];
  const float* r_init  = (const float*)d_in[3];
  float* out           = (float*)d_out;
  const size_t low_bytes = (size_t)NB * SS * HH * sizeof(float);   // 128 MB
  const size_t wt_bytes  = (size_t)HH * LL * sizeof(u16);          // 64 KB
  if (ws_size >= low_bytes + 2 * wt_bytes) {
    float* lowbuf = (float*)d_ws;
    u16* wt_hi = (u16*)((char*)d_ws + low_bytes);
    u16* wt_lo = wt_hi + (size_t)HH * LL;
    hipLaunchKernelGGL(prep_w, dim3(128), dim3(256), 0, stream, Wm, wt_hi, wt_lo);
    hipLaunchKernelGGL(gemm_mfma, dim3(NB * 2), dim3(256), 0, stream,
                       inputs, seq_len, wt_hi, wt_lo, lowbuf);
    hipLaunchKernelGGL(routing2, dim3(NB), dim3(1024), 0, stream,
                       lowbuf, seq_len, r_init, out);
  } else if (ws_size >= low_bytes) {
    float* lowbuf = (float*)d_ws;
    hipLaunchKernelGGL(gemm_low, dim3(NB * 4), dim3(256), 0, stream,
                       inputs, seq_len, Wm, lowbuf);
    hipLaunchKernelGGL(routing2, dim3(NB), dim3(1024), 0, stream,
                       lowbuf, seq_len, r_init, out);
  } else {
    hipLaunchKernelGGL(capsule_fused, dim3(NB), dim3(512), 0, stream,
                       inputs, seq_len, Wm, r_init, out);
  }
}

// Round 6
// 166.594 us; speedup vs baseline: 5.2550x; 1.7975x over previous
//
#include <hip/hip_runtime.h>
#include <hip/hip_bf16.h>

#define NB 1024
#define SS 256
#define LL 256
#define HH 128
#define KMAX 16
#define KE 8

typedef __attribute__((ext_vector_type(8))) short bf16x8;
typedef __attribute__((ext_vector_type(4))) float f32x4;
typedef unsigned short u16;
typedef unsigned int u32;

__device__ __forceinline__ void split_bf16(float a, u16& hi, u16& lo) {
  u32 u = __float_as_uint(a);
  u32 hb = (u + 0x8000u) & 0xFFFF0000u;      // RTN-ish bf16 hi
  float lf = a - __uint_as_float(hb);        // exact residual
  hi = (u16)(hb >> 16);
  lo = (u16)(__float_as_uint(lf) >> 16);     // truncated bf16 lo
}

// ---- prep: W[l][h] -> Wt_hi[h][l], Wt_lo[h][l] (bf16 split, transposed) ----
__global__ __launch_bounds__(256) void prep_w(
    const float* __restrict__ Wm, u16* __restrict__ wt_hi, u16* __restrict__ wt_lo) {
  const int id = blockIdx.x * 256 + threadIdx.x;   // 32768
  const int h = id & 127, l = id >> 7;
  const float a = Wm[(size_t)l * HH + h];
  u16 hi, lo;
  split_bf16(a, hi, lo);
  wt_hi[h * LL + l] = hi;
  wt_lo[h * LL + l] = lo;
}

// ============== Kernel 1: MFMA GEMM, split-bf16 fp32 emulation ==============
#define BM 128
#define BK 32
#define APAD 40   // ushorts/row = 80 B = 20 words

__global__ __launch_bounds__(256, 3) void gemm_mfma(
    const float* __restrict__ inputs, const int* __restrict__ seq_len,
    const u16* __restrict__ wt_hi, const u16* __restrict__ wt_lo,
    float* __restrict__ lowbuf) {
  __shared__ u16 Ahi[BM][APAD], Alo[BM][APAD];
  __shared__ u16 Bhi[HH][APAD], Blo[HH][APAD];

  const int bid = blockIdx.x;
  const int batch = bid >> 1;
  const int r0 = (bid & 1) * BM;
  const int sl = seq_len[batch];
  if (r0 >= sl) return;

  const int t = threadIdx.x;
  const int w = t >> 6;          // wave 0..3 -> rows w*32 .. +31
  const int l = t & 63;
  const int lr = l & 15;
  const int lk = l >> 4;

  f32x4 acc[2][8];
  #pragma unroll
  for (int mt = 0; mt < 2; ++mt)
    #pragma unroll
    for (int nt = 0; nt < 8; ++nt) acc[mt][nt] = (f32x4){0.f, 0.f, 0.f, 0.f};

  const float* Ab = inputs + ((size_t)batch * SS + r0) * LL;
  const int bh = t >> 1, be = t & 1;
  const bool wave_active = (r0 + w * 32) < sl;   // wave-uniform

  for (int kc = 0; kc < LL; kc += BK) {
    // ---- stage A: only rows < sl (saves HBM traffic; stale rows unused) ----
    #pragma unroll
    for (int m = 0; m < 4; ++m) {
      const int g = m * 256 + t;
      const int row = g >> 3, q = g & 7;
      if (r0 + row < sl) {
        const float4 v = *(const float4*)(Ab + (size_t)row * LL + kc + q * 4);
        u16 h0,h1,h2,h3, l0,l1,l2,l3;
        split_bf16(v.x, h0, l0); split_bf16(v.y, h1, l1);
        split_bf16(v.z, h2, l2); split_bf16(v.w, h3, l3);
        uint2 hp, lp;
        hp.x = (u32)h0 | ((u32)h1 << 16);  hp.y = (u32)h2 | ((u32)h3 << 16);
        lp.x = (u32)l0 | ((u32)l1 << 16);  lp.y = (u32)l2 | ((u32)l3 << 16);
        *(uint2*)&Ahi[row][q * 4] = hp;
        *(uint2*)&Alo[row][q * 4] = lp;
      }
    }
    // ---- stage B ----
    {
      const u16* sh = wt_hi + (size_t)bh * LL + kc + be * 16;
      const u16* sv = wt_lo + (size_t)bh * LL + kc + be * 16;
      *(uint4*)&Bhi[bh][be * 16]     = *(const uint4*)(sh);
      *(uint4*)&Bhi[bh][be * 16 + 8] = *(const uint4*)(sh + 8);
      *(uint4*)&Blo[bh][be * 16]     = *(const uint4*)(sv);
      *(uint4*)&Blo[bh][be * 16 + 8] = *(const uint4*)(sv + 8);
    }
    __syncthreads();

    if (wave_active) {
      bf16x8 ah[2], al[2];
      #pragma unroll
      for (int mt = 0; mt < 2; ++mt) {
        const int row = w * 32 + mt * 16 + lr;
        ah[mt] = *(const bf16x8*)&Ahi[row][lk * 8];
        al[mt] = *(const bf16x8*)&Alo[row][lk * 8];
      }
      #pragma unroll
      for (int nt = 0; nt < 8; ++nt) {
        const int col = nt * 16 + lr;
        const bf16x8 bhf = *(const bf16x8*)&Bhi[col][lk * 8];
        const bf16x8 blf = *(const bf16x8*)&Blo[col][lk * 8];
        #pragma unroll
        for (int mt = 0; mt < 2; ++mt) {
          acc[mt][nt] = __builtin_amdgcn_mfma_f32_16x16x32_bf16(ah[mt], bhf, acc[mt][nt], 0, 0, 0);
          acc[mt][nt] = __builtin_amdgcn_mfma_f32_16x16x32_bf16(ah[mt], blf, acc[mt][nt], 0, 0, 0);
          acc[mt][nt] = __builtin_amdgcn_mfma_f32_16x16x32_bf16(al[mt], bhf, acc[mt][nt], 0, 0, 0);
        }
      }
    }
    __syncthreads();
  }

  #pragma unroll
  for (int mt = 0; mt < 2; ++mt)
    #pragma unroll
    for (int j = 0; j < 4; ++j) {
      const int row = r0 + w * 32 + mt * 16 + lk * 4 + j;
      if (row < sl) {
        float* dst = lowbuf + ((size_t)batch * SS + row) * HH;
        #pragma unroll
        for (int nt = 0; nt < 8; ++nt) dst[nt * 16 + lr] = acc[mt][nt][j];
      }
    }
}

// ================= Kernel 2: routing3 (512 thr, spill-free) =================
#define LP 132   // fp32 row stride: quad-bank = (33*s + hquad) % 8 -> floor everywhere

__global__ __launch_bounds__(512) void routing3(
    const float* __restrict__ lowbuf, const int* __restrict__ seq_len,
    const float* __restrict__ r_init, float* __restrict__ out) {
  __shared__ __align__(16) float s_low[SS][LP];      // 135168
  __shared__ __align__(16) float s_p[SS][KE];        //   8192
  __shared__ __align__(16) float s_part[2][KE][HH];  //   8192
  __shared__ __align__(16) float s_high[KE][HH];     //   4096
  __shared__ __align__(16) float s_inv[SS];          //   1024
  __shared__ __align__(16) float s_scale[KE];        //     32  => 156704 B

  const int b = blockIdx.x, t = threadIdx.x, sl = seq_len[b];
  const int w = t >> 6, l = t & 63, half = l >> 5, l31 = l & 31;

  const int ilog = 31 - __clz(sl);
  float nhf = ((sl & (sl - 1)) == 0) ? (float)ilog : log2f((float)sl);
  nhf = fmaxf(1.0f, fminf(16.0f, nhf));
  const int ka = (int)ceilf(nhf);

  // ---- fill (masked rows zeroed) ----
  #pragma unroll
  for (int m = 0; m < 16; ++m) {
    const int idx = m * 512 + t;
    const int s = idx >> 5, q = idx & 31;
    float4 v = make_float4(0.f, 0.f, 0.f, 0.f);
    if (s < sl) v = *(const float4*)(lowbuf + ((size_t)b * SS + s) * HH + q * 4);
    *(float4*)&s_low[s][q * 4] = v;
  }
  #pragma unroll
  for (int m = 0; m < 4; ++m) {
    const int idx = m * 512 + t;
    const int s = idx >> 3, k = idx & 7;
    s_p[s][k] = r_init[((size_t)b * SS + s) * KMAX + k];
  }
  __syncthreads();

  // ---- row inverse norms: lane = row, half = h-half, 1 shuffle ----
  {
    const int s = w * 32 + l31;
    float n2 = 0.f;
    #pragma unroll
    for (int q = 0; q < 16; ++q) {
      const float4 v = *(const float4*)&s_low[s][half * 64 + q * 4];
      n2 = fmaf(v.x, v.x, fmaf(v.y, v.y, fmaf(v.z, v.z, fmaf(v.w, v.w, n2))));
    }
    n2 += __shfl_xor(n2, 32, 64);
    if (half == 0) s_inv[s] = 1.0f / fmaxf(sqrtf(n2), 1e-12f);
  }
  __syncthreads();

  for (int it = 0; it < 3; ++it) {
    // (a) masked softmax over active k
    if (t < SS) {
      const int s = t;
      const float4 ra = *(const float4*)&s_p[s][0];
      const float4 rb = *(const float4*)&s_p[s][4];
      float m = ra.x;
      if (1 < ka) m = fmaxf(m, ra.y);
      if (2 < ka) m = fmaxf(m, ra.z);
      if (3 < ka) m = fmaxf(m, ra.w);
      if (4 < ka) m = fmaxf(m, rb.x);
      if (5 < ka) m = fmaxf(m, rb.y);
      if (6 < ka) m = fmaxf(m, rb.z);
      if (7 < ka) m = fmaxf(m, rb.w);
      const float e0 = expf(ra.x - m);
      const float e1 = (1 < ka) ? expf(ra.y - m) : 0.f;
      const float e2 = (2 < ka) ? expf(ra.z - m) : 0.f;
      const float e3 = (3 < ka) ? expf(ra.w - m) : 0.f;
      const float e4 = (4 < ka) ? expf(rb.x - m) : 0.f;
      const float e5 = (5 < ka) ? expf(rb.y - m) : 0.f;
      const float e6 = (6 < ka) ? expf(rb.z - m) : 0.f;
      const float e7 = (7 < ka) ? expf(rb.w - m) : 0.f;
      const float sum = ((e0 + e1) + (e2 + e3)) + ((e4 + e5) + (e6 + e7));
      const float rs = (s < sl) ? (1.0f / sum) : 0.f;
      *(float4*)&s_p[s][0] = make_float4(e0 * rs, e1 * rs, e2 * rs, e3 * rs);
      *(float4*)&s_p[s][4] = make_float4(e4 * rs, e5 * rs, e6 * rs, e7 * rs);
    }
    __syncthreads();

    // (b) high partials: all 8 waves; wave = (g: s-half, kq: k-pair)
    {
      const int g = w >> 2, kq = w & 3, k0 = kq * 2;
      float a0x = 0.f, a0y = 0.f, a0z = 0.f, a0w = 0.f;
      float a1x = 0.f, a1y = 0.f, a1z = 0.f, a1w = 0.f;
      for (int i = 0; i < 64; ++i) {
        const int s = g * 128 + i * 2 + half;
        const float4 v = *(const float4*)&s_low[s][l31 * 4];
        const float p0 = s_p[s][k0];
        const float p1 = s_p[s][k0 + 1];
        a0x = fmaf(v.x, p0, a0x); a0y = fmaf(v.y, p0, a0y);
        a0z = fmaf(v.z, p0, a0z); a0w = fmaf(v.w, p0, a0w);
        a1x = fmaf(v.x, p1, a1x); a1y = fmaf(v.y, p1, a1y);
        a1z = fmaf(v.z, p1, a1z); a1w = fmaf(v.w, p1, a1w);
      }
      a0x += __shfl_xor(a0x, 32, 64); a0y += __shfl_xor(a0y, 32, 64);
      a0z += __shfl_xor(a0z, 32, 64); a0w += __shfl_xor(a0w, 32, 64);
      a1x += __shfl_xor(a1x, 32, 64); a1y += __shfl_xor(a1y, 32, 64);
      a1z += __shfl_xor(a1z, 32, 64); a1w += __shfl_xor(a1w, 32, 64);
      if (half == 0) {
        *(float4*)&s_part[g][k0][l31 * 4]     = make_float4(a0x, a0y, a0z, a0w);
        *(float4*)&s_part[g][k0 + 1][l31 * 4] = make_float4(a1x, a1y, a1z, a1w);
      }
    }
    __syncthreads();
    #pragma unroll
    for (int m = 0; m < 2; ++m) {
      const int idx = m * 512 + t;
      const int k = idx >> 7, h = idx & 127;
      s_high[k][h] = s_part[0][k][h] + s_part[1][k][h];
    }
    __syncthreads();

    // (c) r[s][k] += inv[s]*dot(high[k],low[s]); lane=row, half=h-half, 1 shuffle/k
    if (it < 2) {
      const int s = w * 32 + l31;
      float d0 = 0.f, d1 = 0.f, d2 = 0.f, d3 = 0.f;
      float d4 = 0.f, d5 = 0.f, d6 = 0.f, d7 = 0.f;
      #pragma unroll
      for (int q = 0; q < 16; ++q) {
        const int h = half * 64 + q * 4;
        const float4 v = *(const float4*)&s_low[s][h];
        const float4 h0 = *(const float4*)&s_high[0][h];
        const float4 h1 = *(const float4*)&s_high[1][h];
        const float4 h2 = *(const float4*)&s_high[2][h];
        const float4 h3 = *(const float4*)&s_high[3][h];
        const float4 h4 = *(const float4*)&s_high[4][h];
        const float4 h5 = *(const float4*)&s_high[5][h];
        const float4 h6 = *(const float4*)&s_high[6][h];
        const float4 h7 = *(const float4*)&s_high[7][h];
        d0 = fmaf(v.x, h0.x, fmaf(v.y, h0.y, fmaf(v.z, h0.z, fmaf(v.w, h0.w, d0))));
        d1 = fmaf(v.x, h1.x, fmaf(v.y, h1.y, fmaf(v.z, h1.z, fmaf(v.w, h1.w, d1))));
        d2 = fmaf(v.x, h2.x, fmaf(v.y, h2.y, fmaf(v.z, h2.z, fmaf(v.w, h2.w, d2))));
        d3 = fmaf(v.x, h3.x, fmaf(v.y, h3.y, fmaf(v.z, h3.z, fmaf(v.w, h3.w, d3))));
        d4 = fmaf(v.x, h4.x, fmaf(v.y, h4.y, fmaf(v.z, h4.z, fmaf(v.w, h4.w, d4))));
        d5 = fmaf(v.x, h5.x, fmaf(v.y, h5.y, fmaf(v.z, h5.z, fmaf(v.w, h5.w, d5))));
        d6 = fmaf(v.x, h6.x, fmaf(v.y, h6.y, fmaf(v.z, h6.z, fmaf(v.w, h6.w, d6))));
        d7 = fmaf(v.x, h7.x, fmaf(v.y, h7.y, fmaf(v.z, h7.z, fmaf(v.w, h7.w, d7))));
      }
      d0 += __shfl_xor(d0, 32, 64); d1 += __shfl_xor(d1, 32, 64);
      d2 += __shfl_xor(d2, 32, 64); d3 += __shfl_xor(d3, 32, 64);
      d4 += __shfl_xor(d4, 32, 64); d5 += __shfl_xor(d5, 32, 64);
      d6 += __shfl_xor(d6, 32, 64); d7 += __shfl_xor(d7, 32, 64);
      if (half == 0) {
        const float inv = s_inv[s];
        float4 p0 = *(const float4*)&s_p[s][0];
        float4 p1 = *(const float4*)&s_p[s][4];
        p0.x = fmaf(d0, inv, p0.x); p0.y = fmaf(d1, inv, p0.y);
        p0.z = fmaf(d2, inv, p0.z); p0.w = fmaf(d3, inv, p0.w);
        p1.x = fmaf(d4, inv, p1.x); p1.y = fmaf(d5, inv, p1.y);
        p1.z = fmaf(d6, inv, p1.z); p1.w = fmaf(d7, inv, p1.w);
        *(float4*)&s_p[s][0] = p0;
        *(float4*)&s_p[s][4] = p1;
      }
    }
    __syncthreads();
  }

  // ---- squash ----
  if (t < 64) {
    const int k = t >> 3, part = t & 7;
    float n2 = 0.f;
    #pragma unroll
    for (int q = 0; q < 4; ++q) {
      const float4 v = *(const float4*)&s_high[k][part * 16 + q * 4];
      n2 = fmaf(v.x, v.x, fmaf(v.y, v.y, fmaf(v.z, v.z, fmaf(v.w, v.w, n2))));
    }
    n2 += __shfl_xor(n2, 1, 64);
    n2 += __shfl_xor(n2, 2, 64);
    n2 += __shfl_xor(n2, 4, 64);
    if (part == 0) {
      const float n = sqrtf(n2), ne = fmaxf(n, 1e-7f), sq = ne * ne;
      float sc = sq / ((1.0f + sq) * ne);
      if (k >= ka) sc = 0.f;
      s_scale[k] = sc;
    }
  }
  __syncthreads();
  {
    float* ob = out + (size_t)b * (KMAX * HH);
    #pragma unroll
    for (int m = 0; m < 2; ++m) {
      const int idx = m * 512 + t;
      const int k = idx >> 7, h = idx & 127;
      ob[k * HH + h]   = s_high[k][h] * s_scale[k];
      ob[KE * HH + idx] = 0.f;                      // capsules 8..15 always zero
    }
    if (t < KMAX)
      out[(size_t)NB * KMAX * HH + (size_t)b * KMAX + t] = (t < ka) ? 1.f : 0.f;
  }
}

// ===================== Fallback: round-3 fused kernel =======================
#define LOWPAD 132
__global__ __launch_bounds__(512) void capsule_fused(
    const float* __restrict__ inputs, const int* __restrict__ seq_len,
    const float* __restrict__ Wm, const float* __restrict__ r_init,
    float* __restrict__ out) {
  __shared__ __align__(16) float s_low[SS][LOWPAD];
  __shared__ __align__(16) float s_p[SS][KE];
  __shared__ __align__(16) float s_part[2][KE][HH];
  __shared__ __align__(16) float s_high[KE][HH];
  __shared__ __align__(16) float s_inv[SS];
  __shared__ __align__(16) float s_scale[KE];
  const int b = blockIdx.x, t = threadIdx.x, sl = seq_len[b];
  const int ilog = 31 - __clz(sl);
  float nh = ((sl & (sl - 1)) == 0) ? (float)ilog : log2f((float)sl);
  nh = fmaxf(1.0f, fminf(16.0f, nh));
  const int ka = (int)ceilf(nh);
  {
    const int hg = t & 15, h0 = hg * 8, rg = t >> 4;
    const float* inb = inputs + (size_t)b * SS * LL;
    for (int sweep = 0; sweep < 8; ++sweep) {
      const int s = sweep * 32 + rg;
      float a0=0.f,a1=0.f,a2=0.f,a3=0.f,a4=0.f,a5=0.f,a6=0.f,a7=0.f;
      if (s < sl) {
        const float* inp = inb + (size_t)s * LL;
        for (int ll = 0; ll < LL; ll += 4) {
          const float4 iv = *(const float4*)(inp + ll);
          #pragma unroll
          for (int d = 0; d < 4; ++d) {
            const float f = (d==0)?iv.x:(d==1)?iv.y:(d==2)?iv.z:iv.w;
            const float* wp = Wm + (size_t)(ll + d) * HH + h0;
            const float4 wa = *(const float4*)(wp);
            const float4 wb = *(const float4*)(wp + 4);
            a0=fmaf(f,wa.x,a0); a1=fmaf(f,wa.y,a1); a2=fmaf(f,wa.z,a2); a3=fmaf(f,wa.w,a3);
            a4=fmaf(f,wb.x,a4); a5=fmaf(f,wb.y,a5); a6=fmaf(f,wb.z,a6); a7=fmaf(f,wb.w,a7);
          }
        }
      }
      s_low[s][h0+0]=a0; s_low[s][h0+1]=a1; s_low[s][h0+2]=a2; s_low[s][h0+3]=a3;
      s_low[s][h0+4]=a4; s_low[s][h0+5]=a5; s_low[s][h0+6]=a6; s_low[s][h0+7]=a7;
    }
  }
  for (int idx = t; idx < SS * KE; idx += 512) {
    const int s = idx >> 3, k = idx & 7;
    s_p[s][k] = r_init[((size_t)b * SS + s) * KMAX + k];
  }
  __syncthreads();
  if (t < SS) {
    float n2 = 0.f;
    for (int h = 0; h < HH; ++h) { const float v = s_low[t][h]; n2 = fmaf(v, v, n2); }
    s_inv[t] = 1.0f / fmaxf(sqrtf(n2), 1e-12f);
  }
  __syncthreads();
  for (int it = 0; it < 3; ++it) {
    if (t < SS) {
      const int s = t;
      float rk0=s_p[s][0],rk1=s_p[s][1],rk2=s_p[s][2],rk3=s_p[s][3];
      float rk4=s_p[s][4],rk5=s_p[s][5],rk6=s_p[s][6],rk7=s_p[s][7];
      float m = rk0;
      if (1<ka) m=fmaxf(m,rk1); if (2<ka) m=fmaxf(m,rk2); if (3<ka) m=fmaxf(m,rk3);
      if (4<ka) m=fmaxf(m,rk4); if (5<ka) m=fmaxf(m,rk5); if (6<ka) m=fmaxf(m,rk6);
      if (7<ka) m=fmaxf(m,rk7);
      const float e0=expf(rk0-m);
      const float e1=(1<ka)?expf(rk1-m):0.f, e2=(2<ka)?expf(rk2-m):0.f;
      const float e3=(3<ka)?expf(rk3-m):0.f, e4=(4<ka)?expf(rk4-m):0.f;
      const float e5=(5<ka)?expf(rk5-m):0.f, e6=(6<ka)?expf(rk6-m):0.f;
      const float e7=(7<ka)?expf(rk7-m):0.f;
      const float sum=((e0+e1)+(e2+e3))+((e4+e5)+(e6+e7));
      const float rs=(s<sl)?(1.0f/sum):0.f;
      s_p[s][0]=e0*rs; s_p[s][1]=e1*rs; s_p[s][2]=e2*rs; s_p[s][3]=e3*rs;
      s_p[s][4]=e4*rs; s_p[s][5]=e5*rs; s_p[s][6]=e6*rs; s_p[s][7]=e7*rs;
    }
    __syncthreads();
    {
      const int g=t>>8, w4=(t>>6)&3, k=(t&63)>>3, hg=t&7, h0=w4*32+hg*4;
      float a0=0.f,a1=0.f,a2=0.f,a3=0.f;
      const int sbase=g*128;
      for (int i=0;i<128;++i) {
        const int s=sbase+i;
        const float4 v=*(const float4*)&s_low[s][h0];
        const float p=s_p[s][k];
        a0=fmaf(v.x,p,a0); a1=fmaf(v.y,p,a1); a2=fmaf(v.z,p,a2); a3=fmaf(v.w,p,a3);
      }
      s_part[g][k][h0+0]=a0; s_part[g][k][h0+1]=a1;
      s_part[g][k][h0+2]=a2; s_part[g][k][h0+3]=a3;
    }
    __syncthreads();
    for (int idx=t; idx<KE*HH; idx+=512) {
      const int k=idx>>7, h=idx&127;
      s_high[k][h]=s_part[0][k][h]+s_part[1][k][h];
    }
    __syncthreads();
    if (it < 2) {
      const int s=t&255, k0=(t>>8)<<2;
      float d0=0.f,d1=0.f,d2=0.f,d3=0.f;
      for (int h=0;h<HH;h+=4) {
        const float4 v=*(const float4*)&s_low[s][h];
        const float4 q0=*(const float4*)&s_high[k0+0][h];
        const float4 q1=*(const float4*)&s_high[k0+1][h];
        const float4 q2=*(const float4*)&s_high[k0+2][h];
        const float4 q3=*(const float4*)&s_high[k0+3][h];
        d0=fmaf(v.x,q0.x,fmaf(v.y,q0.y,fmaf(v.z,q0.z,fmaf(v.w,q0.w,d0))));
        d1=fmaf(v.x,q1.x,fmaf(v.y,q1.y,fmaf(v.z,q1.z,fmaf(v.w,q1.w,d1))));
        d2=fmaf(v.x,q2.x,fmaf(v.y,q2.y,fmaf(v.z,q2.z,fmaf(v.w,q2.w,d2))));
        d3=fmaf(v.x,q3.x,fmaf(v.y,q3.y,fmaf(v.z,q3.z,fmaf(v.w,q3.w,d3))));
      }
      const float inv=s_inv[s];
      s_p[s][k0+0]=fmaf(d0,inv,s_p[s][k0+0]);
      s_p[s][k0+1]=fmaf(d1,inv,s_p[s][k0+1]);
      s_p[s][k0+2]=fmaf(d2,inv,s_p[s][k0+2]);
      s_p[s][k0+3]=fmaf(d3,inv,s_p[s][k0+3]);
    }
    __syncthreads();
  }
  if (t < KE) {
    float n2=0.f;
    for (int h=0;h<HH;++h){ const float v=s_high[t][h]; n2=fmaf(v,v,n2); }
    const float n=sqrtf(n2), ne=fmaxf(n,1e-7f), sq=ne*ne;
    float sc=sq/((1.0f+sq)*ne);
    if (t>=ka) sc=0.f;
    s_scale[t]=sc;
  }
  __syncthreads();
  {
    const int w2=t>>6, lane=t&63;
    const float sc=s_scale[w2];
    float* ob=out+(size_t)b*(KMAX*HH);
    ob[w2*HH+lane]=s_high[w2][lane]*sc;
    ob[w2*HH+lane+64]=s_high[w2][lane+64]*sc;
    ob[KE*HH+t]=0.0f; ob[KE*HH+512+t]=0.0f;
    if (t<KMAX) {
      float* om=out+(size_t)NB*KMAX*HH;
      om[b*KMAX+t]=(t<ka)?1.0f:0.0f;
    }
  }
}

extern "C" void kernel_launch(void* const* d_in, const int* in_sizes, int n_in,
                              void* d_out, int out_size, void* d_ws, size_t ws_size,
                              hipStream_t stream) {
  const float* inputs  = (const float*)d_in[0];
  const int*   seq_len = (const int*)d_in[1];
  const float* Wm      = (const float*)d_in[2];
  const float* r_init  = (const float*)d_in[3];
  float* out           = (float*)d_out;
  const size_t low_bytes = (size_t)NB * SS * HH * sizeof(float);   // 128 MB
  const size_t wt_bytes  = (size_t)HH * LL * sizeof(u16);          // 64 KB
  if (ws_size >= low_bytes + 2 * wt_bytes) {
    float* lowbuf = (float*)d_ws;
    u16* wt_hi = (u16*)((char*)d_ws + low_bytes);
    u16* wt_lo = wt_hi + (size_t)HH * LL;
    hipLaunchKernelGGL(prep_w, dim3(128), dim3(256), 0, stream, Wm, wt_hi, wt_lo);
    hipLaunchKernelGGL(gemm_mfma, dim3(NB * 2), dim3(256), 0, stream,
                       inputs, seq_len, wt_hi, wt_lo, lowbuf);
    hipLaunchKernelGGL(routing3, dim3(NB), dim3(512), 0, stream,
                       lowbuf, seq_len, r_init, out);
  } else {
    hipLaunchKernelGGL(capsule_fused, dim3(NB), dim3(512), 0, stream,
                       inputs, seq_len, Wm, r_init, out);
  }
}

// Round 7
// 165.068 us; speedup vs baseline: 5.3036x; 1.0092x over previous
//
#include <hip/hip_runtime.h>
#include <hip/hip_bf16.h>

#define NB 1024
#define SS 256
#define LL 256
#define HH 128
#define KMAX 16
#define KE 8

typedef __attribute__((ext_vector_type(8))) short bf16x8;
typedef __attribute__((ext_vector_type(4))) float f32x4;
typedef unsigned short u16;
typedef unsigned int u32;

__device__ __forceinline__ void split_bf16(float a, u16& hi, u16& lo) {
  u32 u = __float_as_uint(a);
  u32 hb = (u + 0x8000u) & 0xFFFF0000u;      // RTN-ish bf16 hi
  float lf = a - __uint_as_float(hb);        // exact residual
  hi = (u16)(hb >> 16);
  lo = (u16)(__float_as_uint(lf) >> 16);
}

// ---- prep: W[l][h] -> Wt_hi[h][l], Wt_lo[h][l] (bf16 split, transposed) ----
__global__ __launch_bounds__(256) void prep_w(
    const float* __restrict__ Wm, u16* __restrict__ wt_hi, u16* __restrict__ wt_lo) {
  const int id = blockIdx.x * 256 + threadIdx.x;
  const int h = id & 127, l = id >> 7;
  const float a = Wm[(size_t)l * HH + h];
  u16 hi, lo;
  split_bf16(a, hi, lo);
  wt_hi[h * LL + l] = hi;
  wt_lo[h * LL + l] = lo;
}

// ============== Kernel 1: MFMA GEMM, split-bf16 fp32 emulation ==============
#define BM 128
#define BK 32
#define APAD 40

__global__ __launch_bounds__(256, 3) void gemm_mfma(
    const float* __restrict__ inputs, const int* __restrict__ seq_len,
    const u16* __restrict__ wt_hi, const u16* __restrict__ wt_lo,
    float* __restrict__ lowbuf) {
  __shared__ u16 Ahi[BM][APAD], Alo[BM][APAD];
  __shared__ u16 Bhi[HH][APAD], Blo[HH][APAD];

  const int bid = blockIdx.x;
  const int batch = bid >> 1;
  const int r0 = (bid & 1) * BM;
  const int sl = seq_len[batch];
  if (r0 >= sl) return;

  const int t = threadIdx.x;
  const int w = t >> 6;
  const int l = t & 63;
  const int lr = l & 15;
  const int lk = l >> 4;

  f32x4 acc[2][8];
  #pragma unroll
  for (int mt = 0; mt < 2; ++mt)
    #pragma unroll
    for (int nt = 0; nt < 8; ++nt) acc[mt][nt] = (f32x4){0.f, 0.f, 0.f, 0.f};

  const float* Ab = inputs + ((size_t)batch * SS + r0) * LL;
  const int bh = t >> 1, be = t & 1;
  const bool wave_active = (r0 + w * 32) < sl;

  for (int kc = 0; kc < LL; kc += BK) {
    #pragma unroll
    for (int m = 0; m < 4; ++m) {
      const int g = m * 256 + t;
      const int row = g >> 3, q = g & 7;
      if (r0 + row < sl) {
        const float4 v = *(const float4*)(Ab + (size_t)row * LL + kc + q * 4);
        u16 h0,h1,h2,h3, l0,l1,l2,l3;
        split_bf16(v.x, h0, l0); split_bf16(v.y, h1, l1);
        split_bf16(v.z, h2, l2); split_bf16(v.w, h3, l3);
        uint2 hp, lp;
        hp.x = (u32)h0 | ((u32)h1 << 16);  hp.y = (u32)h2 | ((u32)h3 << 16);
        lp.x = (u32)l0 | ((u32)l1 << 16);  lp.y = (u32)l2 | ((u32)l3 << 16);
        *(uint2*)&Ahi[row][q * 4] = hp;
        *(uint2*)&Alo[row][q * 4] = lp;
      }
    }
    {
      const u16* sh = wt_hi + (size_t)bh * LL + kc + be * 16;
      const u16* sv = wt_lo + (size_t)bh * LL + kc + be * 16;
      *(uint4*)&Bhi[bh][be * 16]     = *(const uint4*)(sh);
      *(uint4*)&Bhi[bh][be * 16 + 8] = *(const uint4*)(sh + 8);
      *(uint4*)&Blo[bh][be * 16]     = *(const uint4*)(sv);
      *(uint4*)&Blo[bh][be * 16 + 8] = *(const uint4*)(sv + 8);
    }
    __syncthreads();

    if (wave_active) {
      bf16x8 ah[2], al[2];
      #pragma unroll
      for (int mt = 0; mt < 2; ++mt) {
        const int row = w * 32 + mt * 16 + lr;
        ah[mt] = *(const bf16x8*)&Ahi[row][lk * 8];
        al[mt] = *(const bf16x8*)&Alo[row][lk * 8];
      }
      #pragma unroll
      for (int nt = 0; nt < 8; ++nt) {
        const int col = nt * 16 + lr;
        const bf16x8 bhf = *(const bf16x8*)&Bhi[col][lk * 8];
        const bf16x8 blf = *(const bf16x8*)&Blo[col][lk * 8];
        #pragma unroll
        for (int mt = 0; mt < 2; ++mt) {
          acc[mt][nt] = __builtin_amdgcn_mfma_f32_16x16x32_bf16(ah[mt], bhf, acc[mt][nt], 0, 0, 0);
          acc[mt][nt] = __builtin_amdgcn_mfma_f32_16x16x32_bf16(ah[mt], blf, acc[mt][nt], 0, 0, 0);
          acc[mt][nt] = __builtin_amdgcn_mfma_f32_16x16x32_bf16(al[mt], bhf, acc[mt][nt], 0, 0, 0);
        }
      }
    }
    __syncthreads();
  }

  #pragma unroll
  for (int mt = 0; mt < 2; ++mt)
    #pragma unroll
    for (int j = 0; j < 4; ++j) {
      const int row = r0 + w * 32 + mt * 16 + lk * 4 + j;
      if (row < sl) {
        float* dst = lowbuf + ((size_t)batch * SS + row) * HH;
        #pragma unroll
        for (int nt = 0; nt < 8; ++nt) dst[nt * 16 + lr] = acc[mt][nt][j];
      }
    }
}

// ============ Kernel 2: routing4 (1024 thr, swizzled, spill-free) ============
// s_low[256][128] word-swizzled: col_stored = col ^ ((s&7)<<2)
__global__ __launch_bounds__(1024) void routing4(
    const float* __restrict__ lowbuf, const int* __restrict__ seq_len,
    const float* __restrict__ r_init, float* __restrict__ out) {
  __shared__ __align__(16) float s_low[SS][HH];      // 131072 (swizzled)
  __shared__ __align__(16) float s_p[SS][KE];        //   8192
  __shared__ __align__(16) float s_part[4][KE][HH];  //  16384
  __shared__ __align__(16) float s_high[KE][HH];     //   4096
  __shared__ __align__(16) float s_inv[SS];          //   1024
  __shared__ __align__(16) float s_scale[KE];        //     32  => 160800 B

  const int b = blockIdx.x, t = threadIdx.x, sl = seq_len[b];
  const int w = t >> 6, l = t & 63, half = l >> 5, l31 = l & 31;

  const int ilog = 31 - __clz(sl);
  float nhf = ((sl & (sl - 1)) == 0) ? (float)ilog : log2f((float)sl);
  nhf = fmaxf(1.0f, fminf(16.0f, nhf));
  const int ka = (int)ceilf(nhf);

  // ---- fill s_low (masked rows zeroed), swizzled; fill s_p ----
  #pragma unroll
  for (int m = 0; m < 8; ++m) {
    const int idx = m * 1024 + t;
    const int s = idx >> 5, q = idx & 31;
    float4 v = make_float4(0.f, 0.f, 0.f, 0.f);
    if (s < sl) v = *(const float4*)(lowbuf + ((size_t)b * SS + s) * HH + q * 4);
    *(float4*)&s_low[s][(q * 4) ^ ((s & 7) << 2)] = v;
  }
  #pragma unroll
  for (int m = 0; m < 2; ++m) {
    const int idx = m * 1024 + t;
    const int s = idx >> 3, k = idx & 7;
    s_p[s][k] = r_init[((size_t)b * SS + s) * KMAX + k];
  }
  __syncthreads();

  // ---- row inverse norms: 4 threads/row, interleaved cols, 2-step butterfly ----
  {
    const int s = t >> 2, hsub = t & 3;
    const int sw = (s & 7) << 2;
    float n2 = 0.f;
    #pragma unroll
    for (int q = 0; q < 8; ++q) {
      const float4 v = *(const float4*)&s_low[s][(q * 16 + hsub * 4) ^ sw];
      n2 = fmaf(v.x, v.x, fmaf(v.y, v.y, fmaf(v.z, v.z, fmaf(v.w, v.w, n2))));
    }
    n2 += __shfl_xor(n2, 1, 64);
    n2 += __shfl_xor(n2, 2, 64);
    if (hsub == 0) s_inv[s] = 1.0f / fmaxf(sqrtf(n2), 1e-12f);
  }
  __syncthreads();

  for (int it = 0; it < 3; ++it) {
    // (a) masked softmax over active k (256 of 1024 threads)
    if (t < SS) {
      const int s = t;
      const float4 ra = *(const float4*)&s_p[s][0];
      const float4 rb = *(const float4*)&s_p[s][4];
      float m = ra.x;
      if (1 < ka) m = fmaxf(m, ra.y);
      if (2 < ka) m = fmaxf(m, ra.z);
      if (3 < ka) m = fmaxf(m, ra.w);
      if (4 < ka) m = fmaxf(m, rb.x);
      if (5 < ka) m = fmaxf(m, rb.y);
      if (6 < ka) m = fmaxf(m, rb.z);
      if (7 < ka) m = fmaxf(m, rb.w);
      const float e0 = expf(ra.x - m);
      const float e1 = (1 < ka) ? expf(ra.y - m) : 0.f;
      const float e2 = (2 < ka) ? expf(ra.z - m) : 0.f;
      const float e3 = (3 < ka) ? expf(ra.w - m) : 0.f;
      const float e4 = (4 < ka) ? expf(rb.x - m) : 0.f;
      const float e5 = (5 < ka) ? expf(rb.y - m) : 0.f;
      const float e6 = (6 < ka) ? expf(rb.z - m) : 0.f;
      const float e7 = (7 < ka) ? expf(rb.w - m) : 0.f;
      const float sum = ((e0 + e1) + (e2 + e3)) + ((e4 + e5) + (e6 + e7));
      const float rs = (s < sl) ? (1.0f / sum) : 0.f;
      *(float4*)&s_p[s][0] = make_float4(e0 * rs, e1 * rs, e2 * rs, e3 * rs);
      *(float4*)&s_p[s][4] = make_float4(e4 * rs, e5 * rs, e6 * rs, e7 * rs);
    }
    __syncthreads();

    // (b) high partials: 16 waves = 4 s-quarters x 4 k-pairs
    {
      const int g = w >> 2, kq = w & 3, k0 = kq * 2;
      float a0x = 0.f, a0y = 0.f, a0z = 0.f, a0w = 0.f;
      float a1x = 0.f, a1y = 0.f, a1z = 0.f, a1w = 0.f;
      #pragma unroll 4
      for (int i = 0; i < 32; ++i) {
        const int s = g * 64 + i * 2 + half;
        const float4 v = *(const float4*)&s_low[s][(l31 * 4) ^ ((s & 7) << 2)];
        const float2 p2 = *(const float2*)&s_p[s][k0];
        a0x = fmaf(v.x, p2.x, a0x); a0y = fmaf(v.y, p2.x, a0y);
        a0z = fmaf(v.z, p2.x, a0z); a0w = fmaf(v.w, p2.x, a0w);
        a1x = fmaf(v.x, p2.y, a1x); a1y = fmaf(v.y, p2.y, a1y);
        a1z = fmaf(v.z, p2.y, a1z); a1w = fmaf(v.w, p2.y, a1w);
      }
      a0x += __shfl_xor(a0x, 32, 64); a0y += __shfl_xor(a0y, 32, 64);
      a0z += __shfl_xor(a0z, 32, 64); a0w += __shfl_xor(a0w, 32, 64);
      a1x += __shfl_xor(a1x, 32, 64); a1y += __shfl_xor(a1y, 32, 64);
      a1z += __shfl_xor(a1z, 32, 64); a1w += __shfl_xor(a1w, 32, 64);
      if (half == 0) {
        *(float4*)&s_part[g][k0][l31 * 4]     = make_float4(a0x, a0y, a0z, a0w);
        *(float4*)&s_part[g][k0 + 1][l31 * 4] = make_float4(a1x, a1y, a1z, a1w);
      }
    }
    __syncthreads();
    {
      const int k = t >> 7, h = t & 127;
      s_high[k][h] = (s_part[0][k][h] + s_part[1][k][h]) +
                     (s_part[2][k][h] + s_part[3][k][h]);
    }
    __syncthreads();

    // (c) r[s][k] += inv[s]*dot(high[k],low[s]): 4 thr/row, interleaved cols
    if (it < 2) {
      const int s = t >> 2, hsub = t & 3;
      const int sw = (s & 7) << 2;
      float d0 = 0.f, d1 = 0.f, d2 = 0.f, d3 = 0.f;
      float d4 = 0.f, d5 = 0.f, d6 = 0.f, d7 = 0.f;
      #pragma unroll
      for (int q = 0; q < 8; ++q) {
        const int col = q * 16 + hsub * 4;
        const float4 v = *(const float4*)&s_low[s][col ^ sw];
        const float4 h0 = *(const float4*)&s_high[0][col];
        const float4 h1 = *(const float4*)&s_high[1][col];
        const float4 h2 = *(const float4*)&s_high[2][col];
        const float4 h3 = *(const float4*)&s_high[3][col];
        const float4 h4 = *(const float4*)&s_high[4][col];
        const float4 h5 = *(const float4*)&s_high[5][col];
        const float4 h6 = *(const float4*)&s_high[6][col];
        const float4 h7 = *(const float4*)&s_high[7][col];
        d0 = fmaf(v.x, h0.x, fmaf(v.y, h0.y, fmaf(v.z, h0.z, fmaf(v.w, h0.w, d0))));
        d1 = fmaf(v.x, h1.x, fmaf(v.y, h1.y, fmaf(v.z, h1.z, fmaf(v.w, h1.w, d1))));
        d2 = fmaf(v.x, h2.x, fmaf(v.y, h2.y, fmaf(v.z, h2.z, fmaf(v.w, h2.w, d2))));
        d3 = fmaf(v.x, h3.x, fmaf(v.y, h3.y, fmaf(v.z, h3.z, fmaf(v.w, h3.w, d3))));
        d4 = fmaf(v.x, h4.x, fmaf(v.y, h4.y, fmaf(v.z, h4.z, fmaf(v.w, h4.w, d4))));
        d5 = fmaf(v.x, h5.x, fmaf(v.y, h5.y, fmaf(v.z, h5.z, fmaf(v.w, h5.w, d5))));
        d6 = fmaf(v.x, h6.x, fmaf(v.y, h6.y, fmaf(v.z, h6.z, fmaf(v.w, h6.w, d6))));
        d7 = fmaf(v.x, h7.x, fmaf(v.y, h7.y, fmaf(v.z, h7.z, fmaf(v.w, h7.w, d7))));
      }
      d0 += __shfl_xor(d0, 1, 64); d0 += __shfl_xor(d0, 2, 64);
      d1 += __shfl_xor(d1, 1, 64); d1 += __shfl_xor(d1, 2, 64);
      d2 += __shfl_xor(d2, 1, 64); d2 += __shfl_xor(d2, 2, 64);
      d3 += __shfl_xor(d3, 1, 64); d3 += __shfl_xor(d3, 2, 64);
      d4 += __shfl_xor(d4, 1, 64); d4 += __shfl_xor(d4, 2, 64);
      d5 += __shfl_xor(d5, 1, 64); d5 += __shfl_xor(d5, 2, 64);
      d6 += __shfl_xor(d6, 1, 64); d6 += __shfl_xor(d6, 2, 64);
      d7 += __shfl_xor(d7, 1, 64); d7 += __shfl_xor(d7, 2, 64);
      if (hsub == 0) {
        const float inv = s_inv[s];
        float4 p0 = *(const float4*)&s_p[s][0];
        float4 p1 = *(const float4*)&s_p[s][4];
        p0.x = fmaf(d0, inv, p0.x); p0.y = fmaf(d1, inv, p0.y);
        p0.z = fmaf(d2, inv, p0.z); p0.w = fmaf(d3, inv, p0.w);
        p1.x = fmaf(d4, inv, p1.x); p1.y = fmaf(d5, inv, p1.y);
        p1.z = fmaf(d6, inv, p1.z); p1.w = fmaf(d7, inv, p1.w);
        *(float4*)&s_p[s][0] = p0;
        *(float4*)&s_p[s][4] = p1;
      }
    }
    __syncthreads();
  }

  // ---- squash ----
  if (t < 64) {
    const int k = t >> 3, part = t & 7;
    float n2 = 0.f;
    #pragma unroll
    for (int q = 0; q < 4; ++q) {
      const float4 v = *(const float4*)&s_high[k][part * 16 + q * 4];
      n2 = fmaf(v.x, v.x, fmaf(v.y, v.y, fmaf(v.z, v.z, fmaf(v.w, v.w, n2))));
    }
    n2 += __shfl_xor(n2, 1, 64);
    n2 += __shfl_xor(n2, 2, 64);
    n2 += __shfl_xor(n2, 4, 64);
    if (part == 0) {
      const float n = sqrtf(n2), ne = fmaxf(n, 1e-7f), sq = ne * ne;
      float sc = sq / ((1.0f + sq) * ne);
      if (k >= ka) sc = 0.f;
      s_scale[k] = sc;
    }
  }
  __syncthreads();
  {
    const int k = t >> 7, h = t & 127;
    float* ob = out + (size_t)b * (KMAX * HH);
    ob[k * HH + h]  = s_high[k][h] * s_scale[k];
    ob[KE * HH + t] = 0.f;
    if (t < KMAX)
      out[(size_t)NB * KMAX * HH + (size_t)b * KMAX + t] = (t < ka) ? 1.f : 0.f;
  }
}

// ===================== Fallback: round-3 fused kernel =======================
#define LOWPAD 132
__global__ __launch_bounds__(512) void capsule_fused(
    const float* __restrict__ inputs, const int* __restrict__ seq_len,
    const float* __restrict__ Wm, const float* __restrict__ r_init,
    float* __restrict__ out) {
  __shared__ __align__(16) float s_low[SS][LOWPAD];
  __shared__ __align__(16) float s_p[SS][KE];
  __shared__ __align__(16) float s_part[2][KE][HH];
  __shared__ __align__(16) float s_high[KE][HH];
  __shared__ __align__(16) float s_inv[SS];
  __shared__ __align__(16) float s_scale[KE];
  const int b = blockIdx.x, t = threadIdx.x, sl = seq_len[b];
  const int ilog = 31 - __clz(sl);
  float nh = ((sl & (sl - 1)) == 0) ? (float)ilog : log2f((float)sl);
  nh = fmaxf(1.0f, fminf(16.0f, nh));
  const int ka = (int)ceilf(nh);
  {
    const int hg = t & 15, h0 = hg * 8, rg = t >> 4;
    const float* inb = inputs + (size_t)b * SS * LL;
    for (int sweep = 0; sweep < 8; ++sweep) {
      const int s = sweep * 32 + rg;
      float a0=0.f,a1=0.f,a2=0.f,a3=0.f,a4=0.f,a5=0.f,a6=0.f,a7=0.f;
      if (s < sl) {
        const float* inp = inb + (size_t)s * LL;
        for (int ll = 0; ll < LL; ll += 4) {
          const float4 iv = *(const float4*)(inp + ll);
          #pragma unroll
          for (int d = 0; d < 4; ++d) {
            const float f = (d==0)?iv.x:(d==1)?iv.y:(d==2)?iv.z:iv.w;
            const float* wp = Wm + (size_t)(ll + d) * HH + h0;
            const float4 wa = *(const float4*)(wp);
            const float4 wb = *(const float4*)(wp + 4);
            a0=fmaf(f,wa.x,a0); a1=fmaf(f,wa.y,a1); a2=fmaf(f,wa.z,a2); a3=fmaf(f,wa.w,a3);
            a4=fmaf(f,wb.x,a4); a5=fmaf(f,wb.y,a5); a6=fmaf(f,wb.z,a6); a7=fmaf(f,wb.w,a7);
          }
        }
      }
      s_low[s][h0+0]=a0; s_low[s][h0+1]=a1; s_low[s][h0+2]=a2; s_low[s][h0+3]=a3;
      s_low[s][h0+4]=a4; s_low[s][h0+5]=a5; s_low[s][h0+6]=a6; s_low[s][h0+7]=a7;
    }
  }
  for (int idx = t; idx < SS * KE; idx += 512) {
    const int s = idx >> 3, k = idx & 7;
    s_p[s][k] = r_init[((size_t)b * SS + s) * KMAX + k];
  }
  __syncthreads();
  if (t < SS) {
    float n2 = 0.f;
    for (int h = 0; h < HH; ++h) { const float v = s_low[t][h]; n2 = fmaf(v, v, n2); }
    s_inv[t] = 1.0f / fmaxf(sqrtf(n2), 1e-12f);
  }
  __syncthreads();
  for (int it = 0; it < 3; ++it) {
    if (t < SS) {
      const int s = t;
      float rk0=s_p[s][0],rk1=s_p[s][1],rk2=s_p[s][2],rk3=s_p[s][3];
      float rk4=s_p[s][4],rk5=s_p[s][5],rk6=s_p[s][6],rk7=s_p[s][7];
      float m = rk0;
      if (1<ka) m=fmaxf(m,rk1); if (2<ka) m=fmaxf(m,rk2); if (3<ka) m=fmaxf(m,rk3);
      if (4<ka) m=fmaxf(m,rk4); if (5<ka) m=fmaxf(m,rk5); if (6<ka) m=fmaxf(m,rk6);
      if (7<ka) m=fmaxf(m,rk7);
      const float e0=expf(rk0-m);
      const float e1=(1<ka)?expf(rk1-m):0.f, e2=(2<ka)?expf(rk2-m):0.f;
      const float e3=(3<ka)?expf(rk3-m):0.f, e4=(4<ka)?expf(rk4-m):0.f;
      const float e5=(5<ka)?expf(rk5-m):0.f, e6=(6<ka)?expf(rk6-m):0.f;
      const float e7=(7<ka)?expf(rk7-m):0.f;
      const float sum=((e0+e1)+(e2+e3))+((e4+e5)+(e6+e7));
      const float rs=(s<sl)?(1.0f/sum):0.f;
      s_p[s][0]=e0*rs; s_p[s][1]=e1*rs; s_p[s][2]=e2*rs; s_p[s][3]=e3*rs;
      s_p[s][4]=e4*rs; s_p[s][5]=e5*rs; s_p[s][6]=e6*rs; s_p[s][7]=e7*rs;
    }
    __syncthreads();
    {
      const int g=t>>8, w4=(t>>6)&3, k=(t&63)>>3, hg=t&7, h0=w4*32+hg*4;
      float a0=0.f,a1=0.f,a2=0.f,a3=0.f;
      const int sbase=g*128;
      for (int i=0;i<128;++i) {
        const int s=sbase+i;
        const float4 v=*(const float4*)&s_low[s][h0];
        const float p=s_p[s][k];
        a0=fmaf(v.x,p,a0); a1=fmaf(v.y,p,a1); a2=fmaf(v.z,p,a2); a3=fmaf(v.w,p,a3);
      }
      s_part[g][k][h0+0]=a0; s_part[g][k][h0+1]=a1;
      s_part[g][k][h0+2]=a2; s_part[g][k][h0+3]=a3;
    }
    __syncthreads();
    for (int idx=t; idx<KE*HH; idx+=512) {
      const int k=idx>>7, h=idx&127;
      s_high[k][h]=s_part[0][k][h]+s_part[1][k][h];
    }
    __syncthreads();
    if (it < 2) {
      const int s=t&255, k0=(t>>8)<<2;
      float d0=0.f,d1=0.f,d2=0.f,d3=0.f;
      for (int h=0;h<HH;h+=4) {
        const float4 v=*(const float4*)&s_low[s][h];
        const float4 q0=*(const float4*)&s_high[k0+0][h];
        const float4 q1=*(const float4*)&s_high[k0+1][h];
        const float4 q2=*(const float4*)&s_high[k0+2][h];
        const float4 q3=*(const float4*)&s_high[k0+3][h];
        d0=fmaf(v.x,q0.x,fmaf(v.y,q0.y,fmaf(v.z,q0.z,fmaf(v.w,q0.w,d0))));
        d1=fmaf(v.x,q1.x,fmaf(v.y,q1.y,fmaf(v.z,q1.z,fmaf(v.w,q1.w,d1))));
        d2=fmaf(v.x,q2.x,fmaf(v.y,q2.y,fmaf(v.z,q2.z,fmaf(v.w,q2.w,d2))));
        d3=fmaf(v.x,q3.x,fmaf(v.y,q3.y,fmaf(v.z,q3.z,fmaf(v.w,q3.w,d3))));
      }
      const float inv=s_inv[s];
      s_p[s][k0+0]=fmaf(d0,inv,s_p[s][k0+0]);
      s_p[s][k0+1]=fmaf(d1,inv,s_p[s][k0+1]);
      s_p[s][k0+2]=fmaf(d2,inv,s_p[s][k0+2]);
      s_p[s][k0+3]=fmaf(d3,inv,s_p[s][k0+3]);
    }
    __syncthreads();
  }
  if (t < KE) {
    float n2=0.f;
    for (int h=0;h<HH;++h){ const float v=s_high[t][h]; n2=fmaf(v,v,n2); }
    const float n=sqrtf(n2), ne=fmaxf(n,1e-7f), sq=ne*ne;
    float sc=sq/((1.0f+sq)*ne);
    if (t>=ka) sc=0.f;
    s_scale[t]=sc;
  }
  __syncthreads();
  {
    const int w2=t>>6, lane=t&63;
    const float sc=s_scale[w2];
    float* ob=out+(size_t)b*(KMAX*HH);
    ob[w2*HH+lane]=s_high[w2][lane]*sc;
    ob[w2*HH+lane+64]=s_high[w2][lane+64]*sc;
    ob[KE*HH+t]=0.0f; ob[KE*HH+512+t]=0.0f;
    if (t<KMAX) {
      float* om=out+(size_t)NB*KMAX*HH;
      om[b*KMAX+t]=(t<ka)?1.0f:0.0f;
    }
  }
}

extern "C" void kernel_launch(void* const* d_in, const int* in_sizes, int n_in,
                              void* d_out, int out_size, void* d_ws, size_t ws_size,
                              hipStream_t stream) {
  const float* inputs  = (const float*)d_in[0];
  const int*   seq_len = (const int*)d_in[1];
  const float* Wm      = (const float*)d_in[2];
  const float* r_init  = (const float*)d_in[3];
  float* out           = (float*)d_out;
  const size_t low_bytes = (size_t)NB * SS * HH * sizeof(float);
  const size_t wt_bytes  = (size_t)HH * LL * sizeof(u16);
  if (ws_size >= low_bytes + 2 * wt_bytes) {
    float* lowbuf = (float*)d_ws;
    u16* wt_hi = (u16*)((char*)d_ws + low_bytes);
    u16* wt_lo = wt_hi + (size_t)HH * LL;
    hipLaunchKernelGGL(prep_w, dim3(128), dim3(256), 0, stream, Wm, wt_hi, wt_lo);
    hipLaunchKernelGGL(gemm_mfma, dim3(NB * 2), dim3(256), 0, stream,
                       inputs, seq_len, wt_hi, wt_lo, lowbuf);
    hipLaunchKernelGGL(routing4, dim3(NB), dim3(1024), 0, stream,
                       lowbuf, seq_len, r_init, out);
  } else {
    hipLaunchKernelGGL(capsule_fused, dim3(NB), dim3(512), 0, stream,
                       inputs, seq_len, Wm, r_init, out);
  }
}